// Round 1
// baseline (612.547 us; speedup 1.0000x reference)
//
#include <hip/hip_runtime.h>
#include <hip/hip_bf16.h>
#include <math.h>

// Problem constants (fixed by reference setup_inputs)
#define BB 16
#define NN 64
#define ATTR 4
#define STATE 16
#define RELD 9
#define GG 32
#define NF 256
#define NROWS_OBJ (BB*NN)        // 1024
#define NROWS_REL (BB*NN*NN)     // 65536

// ---------------------------------------------------------------------------
// 16-row x 256-col tile GEMM accumulator.
// Thread map: c0 = (tid&63)*4 (4 consecutive cols), r0 = (tid>>6)*4 (4 rows).
// A is in LDS (rows x lda floats). W is global, K x 256 row-major.
// Per k-quad: 4 float4 W loads (fully coalesced, L2-resident weights),
// 4 float4 LDS A loads (wave-broadcast, conflict-free), 64 FMAs.
// ---------------------------------------------------------------------------
__device__ __forceinline__ void gemm_acc(float acc[4][4],
    const float* Asm, int lda,
    const float* __restrict__ W, int K, int r0, int c0)
{
  for (int k = 0; k < K; k += 4) {
    float4 wa = *(const float4*)(W + (k + 0) * NF + c0);
    float4 wb = *(const float4*)(W + (k + 1) * NF + c0);
    float4 wc = *(const float4*)(W + (k + 2) * NF + c0);
    float4 wd = *(const float4*)(W + (k + 3) * NF + c0);
#pragma unroll
    for (int r = 0; r < 4; ++r) {
      float4 a = *(const float4*)(Asm + (r0 + r) * lda + k);
      acc[r][0] += a.x * wa.x + a.y * wb.x + a.z * wc.x + a.w * wd.x;
      acc[r][1] += a.x * wa.y + a.y * wb.y + a.z * wc.y + a.w * wd.y;
      acc[r][2] += a.x * wa.z + a.y * wb.z + a.z * wc.z + a.w * wd.z;
      acc[r][3] += a.x * wa.w + a.y * wb.w + a.z * wc.w + a.w * wd.w;
    }
  }
}

__device__ __forceinline__ void init_acc(float acc[4][4], const float* __restrict__ bias, int c0)
{
  if (bias) {
    float4 bb = *(const float4*)(bias + c0);
#pragma unroll
    for (int r = 0; r < 4; ++r) { acc[r][0] = bb.x; acc[r][1] = bb.y; acc[r][2] = bb.z; acc[r][3] = bb.w; }
  } else {
#pragma unroll
    for (int r = 0; r < 4; ++r) { acc[r][0] = 0.f; acc[r][1] = 0.f; acc[r][2] = 0.f; acc[r][3] = 0.f; }
  }
}

__device__ __forceinline__ void store_tile(float* dst, int ldd, float acc[4][4],
                                           int r0, int c0, bool relu)
{
#pragma unroll
  for (int r = 0; r < 4; ++r) {
    float4 v;
    v.x = relu ? fmaxf(acc[r][0], 0.f) : acc[r][0];
    v.y = relu ? fmaxf(acc[r][1], 0.f) : acc[r][1];
    v.z = relu ? fmaxf(acc[r][2], 0.f) : acc[r][2];
    v.w = relu ? fmaxf(acc[r][3], 0.f) : acc[r][3];
    *(float4*)(dst + (r0 + r) * ldd + c0) = v;
  }
}

// ---------------------------------------------------------------------------
// Particle encoder: obj = ReLU(ReLU([attrs,states] @ w0 + b0) @ w1 + b1)
// 64 blocks x 16 rows
// ---------------------------------------------------------------------------
__global__ __launch_bounds__(256) void enc_kernel(
    const float* __restrict__ attrs, const float* __restrict__ states,
    const float* __restrict__ w0, const float* __restrict__ b0,
    const float* __restrict__ w1, const float* __restrict__ b1,
    float* __restrict__ obj)
{
  __shared__ __align__(16) float X[16 * 20];
  __shared__ __align__(16) float H[16 * NF];
  int tid = threadIdx.x;
  int row0 = blockIdx.x * 16;
  for (int idx = tid; idx < 16 * 20; idx += 256) {
    int r = idx / 20, k = idx % 20;
    int m = row0 + r;
    X[idx] = (k < ATTR) ? attrs[m * ATTR + k] : states[m * STATE + (k - ATTR)];
  }
  __syncthreads();
  int c0 = (tid & 63) * 4, r0 = (tid >> 6) * 4;
  float acc[4][4];
  init_acc(acc, b0, c0);
  gemm_acc(acc, X, 20, w0, 20, r0, c0);
  store_tile(H, NF, acc, r0, c0, true);
  __syncthreads();
  init_acc(acc, b1, c0);
  gemm_acc(acc, H, NF, w1, NF, r0, c0);
  store_tile(obj + row0 * NF, NF, acc, r0, c0, true);
}

// ---------------------------------------------------------------------------
// Relation chain (the big one): for each of 65536 (b,i,j) rows,
//   x(33) = [rel_attrs, states_i - states_j, attrs_i, attrs_j]
//   h = ReLU(x @ rel_w0 + rel_b0); e = ReLU(h @ rel_w1 + rel_b1)
//   P = e @ rp_w[0:256]            (no bias/act; bias folded into Q later)
// 4096 blocks x 16 rows. h,e stay in LDS; rel_enc never hits HBM.
// ---------------------------------------------------------------------------
__global__ __launch_bounds__(256) void rel_chain_kernel(
    const float* __restrict__ attrs, const float* __restrict__ states,
    const float* __restrict__ rel_attrs,
    const float* __restrict__ w0, const float* __restrict__ b0,
    const float* __restrict__ w1, const float* __restrict__ b1,
    const float* __restrict__ rpw,
    float* __restrict__ P)
{
  __shared__ __align__(16) float X[16 * 36];  // 33 used, stride 36 (144B = 9*16)
  __shared__ __align__(16) float H[16 * NF];
  __shared__ __align__(16) float E[16 * NF];
  int tid = threadIdx.x;
  int row0 = blockIdx.x * 16;
  for (int idx = tid; idx < 16 * 33; idx += 256) {
    int r = idx / 33, k = idx % 33;
    int grow = row0 + r;
    int j = grow & 63, i = (grow >> 6) & 63, b = grow >> 12;
    float v;
    if (k < RELD)            v = rel_attrs[grow * RELD + k];
    else if (k < RELD+STATE) v = states[(b * NN + i) * STATE + (k - RELD)]
                               - states[(b * NN + j) * STATE + (k - RELD)];
    else if (k < RELD+STATE+ATTR) v = attrs[(b * NN + i) * ATTR + (k - RELD - STATE)];
    else                     v = attrs[(b * NN + j) * ATTR + (k - RELD - STATE - ATTR)];
    X[r * 36 + k] = v;
  }
  __syncthreads();
  int c0 = (tid & 63) * 4, r0 = (tid >> 6) * 4;
  float acc[4][4];
  // stage 1: K=33 (32 vectorized + scalar tail)
  init_acc(acc, b0, c0);
  gemm_acc(acc, X, 36, w0, 32, r0, c0);
  {
    float4 wt = *(const float4*)(w0 + 32 * NF + c0);
#pragma unroll
    for (int r = 0; r < 4; ++r) {
      float a = X[(r0 + r) * 36 + 32];
      acc[r][0] += a * wt.x; acc[r][1] += a * wt.y;
      acc[r][2] += a * wt.z; acc[r][3] += a * wt.w;
    }
  }
  store_tile(H, NF, acc, r0, c0, true);
  __syncthreads();
  // stage 2
  init_acc(acc, b1, c0);
  gemm_acc(acc, H, NF, w1, NF, r0, c0);
  store_tile(E, NF, acc, r0, c0, true);
  __syncthreads();
  // stage 3: P = E @ rpw[0:256,:]
  init_acc(acc, nullptr, c0);
  gemm_acc(acc, E, NF, rpw, NF, r0, c0);
  store_tile(P + (size_t)row0 * NF, NF, acc, r0, c0, false);
}

// ---------------------------------------------------------------------------
// Q = obj @ rp_w[256:512] + rp_b ; R = obj @ rp_w[512:768]
// ---------------------------------------------------------------------------
__global__ __launch_bounds__(256) void qr_kernel(
    const float* __restrict__ obj, const float* __restrict__ rpw,
    const float* __restrict__ rpb, float* __restrict__ Q, float* __restrict__ R)
{
  __shared__ __align__(16) float A[16 * NF];
  int tid = threadIdx.x;
  int row0 = blockIdx.x * 16;
  const float4* src = (const float4*)(obj + row0 * NF);
  float4* dst = (float4*)A;
  for (int i = tid; i < 16 * NF / 4; i += 256) dst[i] = src[i];
  __syncthreads();
  int c0 = (tid & 63) * 4, r0 = (tid >> 6) * 4;
  float acc[4][4];
  init_acc(acc, rpb, c0);
  gemm_acc(acc, A, NF, rpw + 256 * NF, NF, r0, c0);
  store_tile(Q + row0 * NF, NF, acc, r0, c0, false);
  init_acc(acc, nullptr, c0);
  gemm_acc(acc, A, NF, rpw + 512 * NF, NF, r0, c0);
  store_tile(R + row0 * NF, NF, acc, r0, c0, false);
}

// ---------------------------------------------------------------------------
// agg[b,i,:] = sum_j ReLU(P[b,i,j,:] + Q[b,i,:] + R[b,j,:])   (rp_b is in Q)
// 1024 blocks (one per (b,i)), 256 threads = 256 cols. Memory-bound on P.
// ---------------------------------------------------------------------------
__global__ __launch_bounds__(256) void agg_kernel(
    const float* __restrict__ P, const float* __restrict__ Q,
    const float* __restrict__ R, float* __restrict__ agg)
{
  int bi = blockIdx.x;
  int c = threadIdx.x;
  int b = bi >> 6;
  float q = Q[bi * NF + c];
  float s = 0.f;
  const float* Prow = P + (size_t)bi * NN * NF + c;
  const float* Rrow = R + (b * NN) * NF + c;
  for (int j = 0; j < NN; ++j) {
    s += fmaxf(Prow[j * NF] + q + Rrow[j * NF], 0.f);
  }
  agg[bi * NF + c] = s;
}

// ---------------------------------------------------------------------------
// obj_new = ReLU([obj, agg] @ pp_w + pp_b)
// ---------------------------------------------------------------------------
__global__ __launch_bounds__(256) void upd_kernel(
    const float* __restrict__ obj, const float* __restrict__ agg,
    const float* __restrict__ ppw, const float* __restrict__ ppb,
    float* __restrict__ obj_out)
{
  __shared__ __align__(16) float A[16 * NF];
  __shared__ __align__(16) float Gs[16 * NF];
  int tid = threadIdx.x;
  int row0 = blockIdx.x * 16;
  {
    const float4* s1 = (const float4*)(obj + row0 * NF);
    const float4* s2 = (const float4*)(agg + row0 * NF);
    float4* d1 = (float4*)A;
    float4* d2 = (float4*)Gs;
    for (int i = tid; i < 16 * NF / 4; i += 256) { d1[i] = s1[i]; d2[i] = s2[i]; }
  }
  __syncthreads();
  int c0 = (tid & 63) * 4, r0 = (tid >> 6) * 4;
  float acc[4][4];
  init_acc(acc, ppb, c0);
  gemm_acc(acc, A, NF, ppw, NF, r0, c0);
  gemm_acc(acc, Gs, NF, ppw + 256 * NF, NF, r0, c0);
  store_tile(obj_out + row0 * NF, NF, acc, r0, c0, true);
}

// ---------------------------------------------------------------------------
// out = tanh(ReLU(obj @ pred_w0 + pred_b0) @ pred_w1 + pred_b1)
// ---------------------------------------------------------------------------
__global__ __launch_bounds__(256) void pred_kernel(
    const float* __restrict__ obj,
    const float* __restrict__ w0, const float* __restrict__ b0,
    const float* __restrict__ w1, const float* __restrict__ b1,
    float* __restrict__ out)
{
  __shared__ __align__(16) float A[16 * NF];
  __shared__ __align__(16) float T[16 * NF];
  int tid = threadIdx.x;
  int row0 = blockIdx.x * 16;
  {
    const float4* s1 = (const float4*)(obj + row0 * NF);
    float4* d1 = (float4*)A;
    for (int i = tid; i < 16 * NF / 4; i += 256) d1[i] = s1[i];
  }
  __syncthreads();
  int c0 = (tid & 63) * 4, r0 = (tid >> 6) * 4;
  float acc[4][4];
  init_acc(acc, b0, c0);
  gemm_acc(acc, A, NF, w0, NF, r0, c0);
  store_tile(T, NF, acc, r0, c0, true);
  __syncthreads();
  // stage 2: 16 rows x 32 cols = 512 outputs
  for (int idx = tid; idx < 16 * GG; idx += 256) {
    int r = idx >> 5, g = idx & 31;
    float a = b1[g];
    const float* Tr = T + r * NF;
    for (int k = 0; k < NF; ++k) a += Tr[k] * w1[k * GG + g];
    out[(row0 + r) * GG + g] = tanhf(a);
  }
}

extern "C" void kernel_launch(void* const* d_in, const int* in_sizes, int n_in,
                              void* d_out, int out_size, void* d_ws, size_t ws_size,
                              hipStream_t stream)
{
  const float* attrs     = (const float*)d_in[0];
  const float* states    = (const float*)d_in[1];
  const float* rel_attrs = (const float*)d_in[2];
  // d_in[3] = pstep (==2, structural; loop count fixed below)
  const float* enc_w0  = (const float*)d_in[4];
  const float* enc_b0  = (const float*)d_in[5];
  const float* enc_w1  = (const float*)d_in[6];
  const float* enc_b1  = (const float*)d_in[7];
  const float* rel_w0  = (const float*)d_in[8];
  const float* rel_b0  = (const float*)d_in[9];
  const float* rel_w1  = (const float*)d_in[10];
  const float* rel_b1  = (const float*)d_in[11];
  const float* rp_w    = (const float*)d_in[12];
  const float* rp_b    = (const float*)d_in[13];
  const float* pp_w    = (const float*)d_in[14];
  const float* pp_b    = (const float*)d_in[15];
  const float* pred_w0 = (const float*)d_in[16];
  const float* pred_b0 = (const float*)d_in[17];
  const float* pred_w1 = (const float*)d_in[18];
  const float* pred_b1 = (const float*)d_in[19];
  float* out = (float*)d_out;

  char* ws = (char*)d_ws;
  float* P    = (float*)ws;                                  // 65536*256*4 = 64 MB
  float* obj0 = (float*)(ws + (size_t)NROWS_REL * NF * 4);   // 1 MB each below
  float* obj1 = obj0 + NROWS_OBJ * NF;
  float* Q    = obj1 + NROWS_OBJ * NF;
  float* R    = Q + NROWS_OBJ * NF;
  float* agg  = R + NROWS_OBJ * NF;

  enc_kernel<<<NROWS_OBJ / 16, 256, 0, stream>>>(attrs, states, enc_w0, enc_b0,
                                                 enc_w1, enc_b1, obj0);
  rel_chain_kernel<<<NROWS_REL / 16, 256, 0, stream>>>(attrs, states, rel_attrs,
                                                       rel_w0, rel_b0, rel_w1, rel_b1,
                                                       rp_w, P);
  float* cur = obj0; float* nxt = obj1;
  for (int p = 0; p < 2; ++p) {
    qr_kernel<<<NROWS_OBJ / 16, 256, 0, stream>>>(cur, rp_w, rp_b, Q, R);
    agg_kernel<<<NROWS_OBJ, 256, 0, stream>>>(P, Q, R, agg);
    upd_kernel<<<NROWS_OBJ / 16, 256, 0, stream>>>(cur, agg, pp_w, pp_b, nxt);
    float* t = cur; cur = nxt; nxt = t;
  }
  pred_kernel<<<NROWS_OBJ / 16, 256, 0, stream>>>(cur, pred_w0, pred_b0,
                                                  pred_w1, pred_b1, out);
}

// Round 3
// 480.785 us; speedup vs baseline: 1.2741x; 1.2741x over previous
//
#include <hip/hip_runtime.h>
#include <hip/hip_bf16.h>
#include <math.h>

// Problem constants (fixed by reference setup_inputs)
#define BB 16
#define NN 64
#define ATTR 4
#define STATE 16
#define RELD 9
#define GG 32
#define NF 256
#define NROWS_OBJ (BB*NN)        // 1024
#define NROWS_REL (BB*NN*NN)     // 65536

typedef __bf16 bf16x8 __attribute__((ext_vector_type(8)));
typedef float  floatx4 __attribute__((ext_vector_type(4)));
typedef unsigned short ushort_t;

__device__ __forceinline__ ushort_t f2bf(float f) {
  unsigned int u = __float_as_uint(f);
  unsigned int r = (u + 0x7fffu + ((u >> 16) & 1u)) >> 16;
  return (ushort_t)r;
}
__device__ __forceinline__ float bf2f(ushort_t u) {
  return __uint_as_float(((unsigned int)u) << 16);
}
// bf16x3 split: x ~= h + l with |x-(h+l)| ~ 2^-18 |x|
__device__ __forceinline__ void split2(float x, ushort_t& h, ushort_t& l) {
  h = f2bf(x);
  float r = x - bf2f(h);
  l = f2bf(r);
}

// ---------------------------------------------------------------------------
// Weight prep: bf16x3 split transposed copies (Wt[n][k], h and l parts).
// Wt0: rel_w0 (33x256 -> 256x64, zero-padded K). Wt1: rel_w1. Wt2: rp_w[0:256].
// ---------------------------------------------------------------------------
__global__ __launch_bounds__(256) void wprep_kernel(
    const float* __restrict__ w0, const float* __restrict__ w1,
    const float* __restrict__ rpw,
    ushort_t* __restrict__ Wt0h, ushort_t* __restrict__ Wt0l,
    ushort_t* __restrict__ Wt1h, ushort_t* __restrict__ Wt1l,
    ushort_t* __restrict__ Wt2h, ushort_t* __restrict__ Wt2l)
{
  int idx = blockIdx.x * 256 + threadIdx.x;
  if (idx < 256 * 64) {
    int n = idx >> 6, k = idx & 63;
    float v = (k < 33) ? w0[k * NF + n] : 0.f;
    split2(v, Wt0h[idx], Wt0l[idx]);
  } else if (idx < 256 * 64 + 256 * 256) {
    int t = idx - 256 * 64;
    int n = t >> 8, k = t & 255;
    split2(w1[k * NF + n], Wt1h[t], Wt1l[t]);
  } else if (idx < 256 * 64 + 2 * 256 * 256) {
    int t = idx - (256 * 64 + 256 * 256);
    int n = t >> 8, k = t & 255;
    split2(rpw[k * NF + n], Wt2h[t], Wt2l[t]);
  }
}

// ---------------------------------------------------------------------------
// Relation chain via bf16x3 split MFMA (fp32-equivalent accuracy).
// 2048 blocks x 32 rows. 4 waves; wave w owns cols [64w,64w+64): 2x4 tiles.
// LDS: X split (stride 72: 2-way bank alias only, free) + H split (stride 264).
// E overwrites H's region after a barrier (H fully consumed). 42KB/WG.
// Per product: 3 MFMAs (AhBh + AhBl + AlBh). P written fp32 (error amplifiers
// in agg act on exact values). Layouts verified m89/m120.
// ---------------------------------------------------------------------------
#define ROWS 32
#define HSTR 264
#define XSTR 72

__global__ __launch_bounds__(256) void rel_chain_mfma(
    const float* __restrict__ attrs, const float* __restrict__ states,
    const float* __restrict__ rel_attrs,
    const ushort_t* __restrict__ Wt0h, const ushort_t* __restrict__ Wt0l,
    const float* __restrict__ b0,
    const ushort_t* __restrict__ Wt1h, const ushort_t* __restrict__ Wt1l,
    const float* __restrict__ b1,
    const ushort_t* __restrict__ Wt2h, const ushort_t* __restrict__ Wt2l,
    float* __restrict__ P)
{
  __shared__ __align__(16) ushort_t Hh[ROWS * HSTR];
  __shared__ __align__(16) ushort_t Hl[ROWS * HSTR];
  __shared__ __align__(16) ushort_t Xh[ROWS * XSTR];
  __shared__ __align__(16) ushort_t Xl[ROWS * XSTR];

  int tid  = threadIdx.x;
  int wave = tid >> 6;
  int lane = tid & 63;
  int quad = lane >> 4;
  int l16  = lane & 15;
  int row0 = blockIdx.x * ROWS;

  // Build X (32 rows x 33 cols, zero-padded to 64), split bf16
  for (int idx = tid; idx < ROWS * 64; idx += 256) {
    int r = idx >> 6, k = idx & 63;
    int grow = row0 + r;
    int j = grow & 63, i = (grow >> 6) & 63, b = grow >> 12;
    float v = 0.f;
    if (k < RELD)                     v = rel_attrs[(size_t)grow * RELD + k];
    else if (k < RELD + STATE)        v = states[(b * NN + i) * STATE + (k - RELD)]
                                        - states[(b * NN + j) * STATE + (k - RELD)];
    else if (k < RELD + STATE + ATTR) v = attrs[(b * NN + i) * ATTR + (k - RELD - STATE)];
    else if (k < 33)                  v = attrs[(b * NN + j) * ATTR + (k - RELD - STATE - ATTR)];
    ushort_t h, l; split2(v, h, l);
    Xh[r * XSTR + k] = h;
    Xl[r * XSTR + k] = l;
  }
  __syncthreads();

  int n_base = wave * 64;
  floatx4 acc[2][4];

#define ZERO_ACC() do { \
  _Pragma("unroll") for (int rt = 0; rt < 2; ++rt) \
  _Pragma("unroll") for (int ct = 0; ct < 4; ++ct) acc[rt][ct] = (floatx4)(0.f); } while (0)

#define MFMA3_STEP(AH, AL, WH, WL, KW, KOFF) do { \
  bf16x8 ah[2], al[2], bh[4], bl[4]; \
  _Pragma("unroll") for (int rt = 0; rt < 2; ++rt) { \
    ah[rt] = *(const bf16x8*)(&(AH)[(rt * 16 + l16) * (KOFF) + k0 + quad * 8]); \
    al[rt] = *(const bf16x8*)(&(AL)[(rt * 16 + l16) * (KOFF) + k0 + quad * 8]); \
  } \
  _Pragma("unroll") for (int ct = 0; ct < 4; ++ct) { \
    bh[ct] = *(const bf16x8*)(&(WH)[(n_base + ct * 16 + l16) * (KW) + k0 + quad * 8]); \
    bl[ct] = *(const bf16x8*)(&(WL)[(n_base + ct * 16 + l16) * (KW) + k0 + quad * 8]); \
  } \
  _Pragma("unroll") for (int rt = 0; rt < 2; ++rt) \
  _Pragma("unroll") for (int ct = 0; ct < 4; ++ct) { \
    acc[rt][ct] = __builtin_amdgcn_mfma_f32_16x16x32_bf16(ah[rt], bh[ct], acc[rt][ct], 0, 0, 0); \
    acc[rt][ct] = __builtin_amdgcn_mfma_f32_16x16x32_bf16(ah[rt], bl[ct], acc[rt][ct], 0, 0, 0); \
    acc[rt][ct] = __builtin_amdgcn_mfma_f32_16x16x32_bf16(al[rt], bh[ct], acc[rt][ct], 0, 0, 0); \
  } } while (0)

  // ---- stage 1: H = ReLU(X @ W0 + b0), K=64 (padded)
  ZERO_ACC();
#pragma unroll
  for (int k0 = 0; k0 < 64; k0 += 32) MFMA3_STEP(Xh, Xl, Wt0h, Wt0l, 64, XSTR);
#pragma unroll
  for (int ct = 0; ct < 4; ++ct) {
    int col = n_base + ct * 16 + l16;
    float bias = b0[col];
#pragma unroll
    for (int rt = 0; rt < 2; ++rt)
#pragma unroll
      for (int r = 0; r < 4; ++r) {
        int row = rt * 16 + quad * 4 + r;
        float h = fmaxf(acc[rt][ct][r] + bias, 0.f);
        split2(h, Hh[row * HSTR + col], Hl[row * HSTR + col]);
      }
  }
  __syncthreads();

  // ---- stage 2: E = ReLU(H @ W1 + b1), K=256
  ZERO_ACC();
  for (int k0 = 0; k0 < 256; k0 += 32) MFMA3_STEP(Hh, Hl, Wt1h, Wt1l, 256, HSTR);
  __syncthreads();  // all H reads done before overwriting region with E
#pragma unroll
  for (int ct = 0; ct < 4; ++ct) {
    int col = n_base + ct * 16 + l16;
    float bias = b1[col];
#pragma unroll
    for (int rt = 0; rt < 2; ++rt)
#pragma unroll
      for (int r = 0; r < 4; ++r) {
        int row = rt * 16 + quad * 4 + r;
        float e = fmaxf(acc[rt][ct][r] + bias, 0.f);
        split2(e, Hh[row * HSTR + col], Hl[row * HSTR + col]);
      }
  }
  __syncthreads();

  // ---- stage 3: P = E @ W2 (rp_b folded into Q), K=256, fp32 out
  ZERO_ACC();
  for (int k0 = 0; k0 < 256; k0 += 32) MFMA3_STEP(Hh, Hl, Wt2h, Wt2l, 256, HSTR);
#pragma unroll
  for (int ct = 0; ct < 4; ++ct) {
    int col = n_base + ct * 16 + l16;
#pragma unroll
    for (int rt = 0; rt < 2; ++rt)
#pragma unroll
      for (int r = 0; r < 4; ++r) {
        int row = rt * 16 + quad * 4 + r;
        P[(size_t)(row0 + row) * NF + col] = acc[rt][ct][r];
      }
  }
#undef ZERO_ACC
#undef MFMA3_STEP
}

// ---------------------------------------------------------------------------
// fp32 16-row x 256-col tile GEMM helpers (small kernels — unchanged from R0)
// ---------------------------------------------------------------------------
__device__ __forceinline__ void gemm_acc(float acc[4][4],
    const float* Asm, int lda,
    const float* __restrict__ W, int K, int r0, int c0)
{
  for (int k = 0; k < K; k += 4) {
    float4 wa = *(const float4*)(W + (k + 0) * NF + c0);
    float4 wb = *(const float4*)(W + (k + 1) * NF + c0);
    float4 wc = *(const float4*)(W + (k + 2) * NF + c0);
    float4 wd = *(const float4*)(W + (k + 3) * NF + c0);
#pragma unroll
    for (int r = 0; r < 4; ++r) {
      float4 a = *(const float4*)(Asm + (r0 + r) * lda + k);
      acc[r][0] += a.x * wa.x + a.y * wb.x + a.z * wc.x + a.w * wd.x;
      acc[r][1] += a.x * wa.y + a.y * wb.y + a.z * wc.y + a.w * wd.y;
      acc[r][2] += a.x * wa.z + a.y * wb.z + a.z * wc.z + a.w * wd.z;
      acc[r][3] += a.x * wa.w + a.y * wb.w + a.z * wc.w + a.w * wd.w;
    }
  }
}

__device__ __forceinline__ void init_acc(float acc[4][4], const float* __restrict__ bias, int c0)
{
  if (bias) {
    float4 bb = *(const float4*)(bias + c0);
#pragma unroll
    for (int r = 0; r < 4; ++r) { acc[r][0] = bb.x; acc[r][1] = bb.y; acc[r][2] = bb.z; acc[r][3] = bb.w; }
  } else {
#pragma unroll
    for (int r = 0; r < 4; ++r) { acc[r][0] = 0.f; acc[r][1] = 0.f; acc[r][2] = 0.f; acc[r][3] = 0.f; }
  }
}

__device__ __forceinline__ void store_tile(float* dst, int ldd, float acc[4][4],
                                           int r0, int c0, bool relu)
{
#pragma unroll
  for (int r = 0; r < 4; ++r) {
    float4 v;
    v.x = relu ? fmaxf(acc[r][0], 0.f) : acc[r][0];
    v.y = relu ? fmaxf(acc[r][1], 0.f) : acc[r][1];
    v.z = relu ? fmaxf(acc[r][2], 0.f) : acc[r][2];
    v.w = relu ? fmaxf(acc[r][3], 0.f) : acc[r][3];
    *(float4*)(dst + (r0 + r) * ldd + c0) = v;
  }
}

__global__ __launch_bounds__(256) void enc_kernel(
    const float* __restrict__ attrs, const float* __restrict__ states,
    const float* __restrict__ w0, const float* __restrict__ b0,
    const float* __restrict__ w1, const float* __restrict__ b1,
    float* __restrict__ obj)
{
  __shared__ __align__(16) float X[16 * 20];
  __shared__ __align__(16) float H[16 * NF];
  int tid = threadIdx.x;
  int row0 = blockIdx.x * 16;
  for (int idx = tid; idx < 16 * 20; idx += 256) {
    int r = idx / 20, k = idx % 20;
    int m = row0 + r;
    X[idx] = (k < ATTR) ? attrs[m * ATTR + k] : states[m * STATE + (k - ATTR)];
  }
  __syncthreads();
  int c0 = (tid & 63) * 4, r0 = (tid >> 6) * 4;
  float acc[4][4];
  init_acc(acc, b0, c0);
  gemm_acc(acc, X, 20, w0, 20, r0, c0);
  store_tile(H, NF, acc, r0, c0, true);
  __syncthreads();
  init_acc(acc, b1, c0);
  gemm_acc(acc, H, NF, w1, NF, r0, c0);
  store_tile(obj + row0 * NF, NF, acc, r0, c0, true);
}

__global__ __launch_bounds__(256) void qr_kernel(
    const float* __restrict__ obj, const float* __restrict__ rpw,
    const float* __restrict__ rpb, float* __restrict__ Q, float* __restrict__ R)
{
  __shared__ __align__(16) float A[16 * NF];
  int tid = threadIdx.x;
  int row0 = blockIdx.x * 16;
  const float4* src = (const float4*)(obj + row0 * NF);
  float4* dst = (float4*)A;
  for (int i = tid; i < 16 * NF / 4; i += 256) dst[i] = src[i];
  __syncthreads();
  int c0 = (tid & 63) * 4, r0 = (tid >> 6) * 4;
  float acc[4][4];
  init_acc(acc, rpb, c0);
  gemm_acc(acc, A, NF, rpw + 256 * NF, NF, r0, c0);
  store_tile(Q + row0 * NF, NF, acc, r0, c0, false);
  init_acc(acc, nullptr, c0);
  gemm_acc(acc, A, NF, rpw + 512 * NF, NF, r0, c0);
  store_tile(R + row0 * NF, NF, acc, r0, c0, false);
}

// agg[b,i,:] = sum_j ReLU(P[b,i,j,:] + Q[b,i,:] + R[b,j,:])   (P fp32)
__global__ __launch_bounds__(256) void agg_kernel(
    const float* __restrict__ P, const float* __restrict__ Q,
    const float* __restrict__ R, float* __restrict__ agg)
{
  int bi = blockIdx.x;
  int c = threadIdx.x;
  int b = bi >> 6;
  float q = Q[bi * NF + c];
  float s = 0.f;
  const float* Prow = P + (size_t)bi * NN * NF + c;
  const float* Rrow = R + (b * NN) * NF + c;
  for (int j = 0; j < NN; ++j) {
    s += fmaxf(Prow[j * NF] + q + Rrow[j * NF], 0.f);
  }
  agg[bi * NF + c] = s;
}

__global__ __launch_bounds__(256) void upd_kernel(
    const float* __restrict__ obj, const float* __restrict__ agg,
    const float* __restrict__ ppw, const float* __restrict__ ppb,
    float* __restrict__ obj_out)
{
  __shared__ __align__(16) float A[16 * NF];
  __shared__ __align__(16) float Gs[16 * NF];
  int tid = threadIdx.x;
  int row0 = blockIdx.x * 16;
  {
    const float4* s1 = (const float4*)(obj + row0 * NF);
    const float4* s2 = (const float4*)(agg + row0 * NF);
    float4* d1 = (float4*)A;
    float4* d2 = (float4*)Gs;
    for (int i = tid; i < 16 * NF / 4; i += 256) { d1[i] = s1[i]; d2[i] = s2[i]; }
  }
  __syncthreads();
  int c0 = (tid & 63) * 4, r0 = (tid >> 6) * 4;
  float acc[4][4];
  init_acc(acc, ppb, c0);
  gemm_acc(acc, A, NF, ppw, NF, r0, c0);
  gemm_acc(acc, Gs, NF, ppw + 256 * NF, NF, r0, c0);
  store_tile(obj_out + row0 * NF, NF, acc, r0, c0, true);
}

__global__ __launch_bounds__(256) void pred_kernel(
    const float* __restrict__ obj,
    const float* __restrict__ w0, const float* __restrict__ b0,
    const float* __restrict__ w1, const float* __restrict__ b1,
    float* __restrict__ out)
{
  __shared__ __align__(16) float A[16 * NF];
  __shared__ __align__(16) float T[16 * NF];
  int tid = threadIdx.x;
  int row0 = blockIdx.x * 16;
  {
    const float4* s1 = (const float4*)(obj + row0 * NF);
    float4* d1 = (float4*)A;
    for (int i = tid; i < 16 * NF / 4; i += 256) d1[i] = s1[i];
  }
  __syncthreads();
  int c0 = (tid & 63) * 4, r0 = (tid >> 6) * 4;
  float acc[4][4];
  init_acc(acc, b0, c0);
  gemm_acc(acc, A, NF, w0, NF, r0, c0);
  store_tile(T, NF, acc, r0, c0, true);
  __syncthreads();
  for (int idx = tid; idx < 16 * GG; idx += 256) {
    int r = idx >> 5, g = idx & 31;
    float a = b1[g];
    const float* Tr = T + r * NF;
    for (int k = 0; k < NF; ++k) a += Tr[k] * w1[k * GG + g];
    out[(row0 + r) * GG + g] = tanhf(a);
  }
}

extern "C" void kernel_launch(void* const* d_in, const int* in_sizes, int n_in,
                              void* d_out, int out_size, void* d_ws, size_t ws_size,
                              hipStream_t stream)
{
  const float* attrs     = (const float*)d_in[0];
  const float* states    = (const float*)d_in[1];
  const float* rel_attrs = (const float*)d_in[2];
  // d_in[3] = pstep (==2, structural)
  const float* enc_w0  = (const float*)d_in[4];
  const float* enc_b0  = (const float*)d_in[5];
  const float* enc_w1  = (const float*)d_in[6];
  const float* enc_b1  = (const float*)d_in[7];
  const float* rel_w0  = (const float*)d_in[8];
  const float* rel_b0  = (const float*)d_in[9];
  const float* rel_w1  = (const float*)d_in[10];
  const float* rel_b1  = (const float*)d_in[11];
  const float* rp_w    = (const float*)d_in[12];
  const float* rp_b    = (const float*)d_in[13];
  const float* pp_w    = (const float*)d_in[14];
  const float* pp_b    = (const float*)d_in[15];
  const float* pred_w0 = (const float*)d_in[16];
  const float* pred_b0 = (const float*)d_in[17];
  const float* pred_w1 = (const float*)d_in[18];
  const float* pred_b1 = (const float*)d_in[19];
  float* out = (float*)d_out;

  char* ws = (char*)d_ws;
  float* P    = (float*)ws;                                  // 65536*256*4 = 64 MB
  float* obj0 = P + (size_t)NROWS_REL * NF;
  float* obj1 = obj0 + NROWS_OBJ * NF;
  float* Q    = obj1 + NROWS_OBJ * NF;
  float* R    = Q + NROWS_OBJ * NF;
  float* agg  = R + NROWS_OBJ * NF;
  ushort_t* Wt0h = (ushort_t*)(agg + NROWS_OBJ * NF);        // 256*64 each
  ushort_t* Wt0l = Wt0h + 256 * 64;
  ushort_t* Wt1h = Wt0l + 256 * 64;                          // 256*256 each
  ushort_t* Wt1l = Wt1h + 256 * 256;
  ushort_t* Wt2h = Wt1l + 256 * 256;
  ushort_t* Wt2l = Wt2h + 256 * 256;

  wprep_kernel<<<(256*64 + 2*256*256 + 255) / 256, 256, 0, stream>>>(
      rel_w0, rel_w1, rp_w, Wt0h, Wt0l, Wt1h, Wt1l, Wt2h, Wt2l);
  enc_kernel<<<NROWS_OBJ / 16, 256, 0, stream>>>(attrs, states, enc_w0, enc_b0,
                                                 enc_w1, enc_b1, obj0);
  rel_chain_mfma<<<NROWS_REL / ROWS, 256, 0, stream>>>(attrs, states, rel_attrs,
                                                       Wt0h, Wt0l, rel_b0,
                                                       Wt1h, Wt1l, rel_b1,
                                                       Wt2h, Wt2l, P);
  float* cur = obj0; float* nxt = obj1;
  for (int p = 0; p < 2; ++p) {
    qr_kernel<<<NROWS_OBJ / 16, 256, 0, stream>>>(cur, rp_w, rp_b, Q, R);
    agg_kernel<<<NROWS_OBJ, 256, 0, stream>>>(P, Q, R, agg);
    upd_kernel<<<NROWS_OBJ / 16, 256, 0, stream>>>(cur, agg, pp_w, pp_b, nxt);
    float* t = cur; cur = nxt; nxt = t;
  }
  pred_kernel<<<NROWS_OBJ / 16, 256, 0, stream>>>(cur, pred_w0, pred_b0,
                                                  pred_w1, pred_b1, out);
}

// Round 4
// 398.099 us; speedup vs baseline: 1.5387x; 1.2077x over previous
//
#include <hip/hip_runtime.h>
#include <hip/hip_bf16.h>
#include <math.h>

// Problem constants (fixed by reference setup_inputs)
#define BB 16
#define NN 64
#define ATTR 4
#define STATE 16
#define RELD 9
#define GG 32
#define NF 256
#define NROWS_OBJ (BB*NN)        // 1024
#define NROWS_REL (BB*NN*NN)     // 65536

typedef __bf16 bf16x8 __attribute__((ext_vector_type(8)));
typedef float  floatx4 __attribute__((ext_vector_type(4)));
typedef unsigned short ushort_t;

__device__ __forceinline__ ushort_t f2bf(float f) {
  unsigned int u = __float_as_uint(f);
  unsigned int r = (u + 0x7fffu + ((u >> 16) & 1u)) >> 16;
  return (ushort_t)r;
}
__device__ __forceinline__ float bf2f(ushort_t u) {
  return __uint_as_float(((unsigned int)u) << 16);
}
// bf16x3 split: x ~= h + l with |x-(h+l)| ~ 2^-18 |x|
__device__ __forceinline__ void split2(float x, ushort_t& h, ushort_t& l) {
  h = f2bf(x);
  float r = x - bf2f(h);
  l = f2bf(r);
}

// ---------------------------------------------------------------------------
// Weight prep: bf16x3 split weights in MFMA FRAGMENT-STREAM order:
//   F[((s*16 + g)*64 + lane)*8 + j] = W[k = s*32 + (lane>>4)*8 + j][n = g*16 + (lane&15)]
// so a wave's B-fragment load is base + lane*16B — one coalesced 1KB transaction.
// F0: rel_w0 (33x256, K zero-padded to 64, S=2). F1: rel_w1 (S=8). F2: rp_w[0:256] (S=8).
// ---------------------------------------------------------------------------
#define F0_ELEMS (2 * 16 * 64 * 8)   // 16384
#define F1_ELEMS (8 * 16 * 64 * 8)   // 65536

__global__ __launch_bounds__(256) void wprep_kernel(
    const float* __restrict__ w0, const float* __restrict__ w1,
    const float* __restrict__ rpw,
    ushort_t* __restrict__ F0h, ushort_t* __restrict__ F0l,
    ushort_t* __restrict__ F1h, ushort_t* __restrict__ F1l,
    ushort_t* __restrict__ F2h, ushort_t* __restrict__ F2l)
{
  int idx = blockIdx.x * 256 + threadIdx.x;
  if (idx < F0_ELEMS) {
    int j = idx & 7, lane = (idx >> 3) & 63, g = (idx >> 9) & 15, s = idx >> 13;
    int k = s * 32 + (lane >> 4) * 8 + j, n = g * 16 + (lane & 15);
    float v = (k < 33) ? w0[k * NF + n] : 0.f;
    split2(v, F0h[idx], F0l[idx]);
    return;
  }
  int t = idx - F0_ELEMS;
  if (t < F1_ELEMS) {
    int j = t & 7, lane = (t >> 3) & 63, g = (t >> 9) & 15, s = t >> 13;
    int k = s * 32 + (lane >> 4) * 8 + j, n = g * 16 + (lane & 15);
    split2(w1[k * NF + n], F1h[t], F1l[t]);
    return;
  }
  t -= F1_ELEMS;
  if (t < F1_ELEMS) {
    int j = t & 7, lane = (t >> 3) & 63, g = (t >> 9) & 15, s = t >> 13;
    int k = s * 32 + (lane >> 4) * 8 + j, n = g * 16 + (lane & 15);
    split2(rpw[k * NF + n], F2h[t], F2l[t]);
  }
}

// ---------------------------------------------------------------------------
// Relation chain via bf16x3 split MFMA, software-pipelined.
// 2048 blocks x 32 rows; wave w owns cols [64w,64w+64): 2x4 tiles of 16x16.
// B-fragments: coalesced stream loads (layout above), register double-buffered.
// A-fragments: LDS (strides 72/264 ushorts -> b128 reads spread over all 8
// bank-groups), register double-buffered. 24 MFMAs hide next step's loads.
// P written fp32 (agg's x8..x32 error amplifiers act on exact values).
// ---------------------------------------------------------------------------
#define ROWS 32
#define HSTR 264
#define XSTR 72

__global__ __launch_bounds__(256, 3) void rel_chain_mfma(
    const float* __restrict__ attrs, const float* __restrict__ states,
    const float* __restrict__ rel_attrs,
    const ushort_t* __restrict__ F0h, const ushort_t* __restrict__ F0l,
    const float* __restrict__ b0,
    const ushort_t* __restrict__ F1h, const ushort_t* __restrict__ F1l,
    const float* __restrict__ b1,
    const ushort_t* __restrict__ F2h, const ushort_t* __restrict__ F2l,
    float* __restrict__ P)
{
  __shared__ __align__(16) ushort_t Hh[ROWS * HSTR];
  __shared__ __align__(16) ushort_t Hl[ROWS * HSTR];
  __shared__ __align__(16) ushort_t Xh[ROWS * XSTR];
  __shared__ __align__(16) ushort_t Xl[ROWS * XSTR];

  int tid  = threadIdx.x;
  int wave = tid >> 6;
  int lane = tid & 63;
  int quad = lane >> 4;
  int l16  = lane & 15;
  int row0 = blockIdx.x * ROWS;

  // Build X (32 rows x 33 cols, zero-padded to 64), split bf16
  for (int idx = tid; idx < ROWS * 64; idx += 256) {
    int r = idx >> 6, k = idx & 63;
    int grow = row0 + r;
    int j = grow & 63, i = (grow >> 6) & 63, b = grow >> 12;
    float v = 0.f;
    if (k < RELD)                     v = rel_attrs[(size_t)grow * RELD + k];
    else if (k < RELD + STATE)        v = states[(b * NN + i) * STATE + (k - RELD)]
                                        - states[(b * NN + j) * STATE + (k - RELD)];
    else if (k < RELD + STATE + ATTR) v = attrs[(b * NN + i) * ATTR + (k - RELD - STATE)];
    else if (k < 33)                  v = attrs[(b * NN + j) * ATTR + (k - RELD - STATE - ATTR)];
    ushort_t h, l; split2(v, h, l);
    Xh[r * XSTR + k] = h;
    Xl[r * XSTR + k] = l;
  }
  __syncthreads();

  floatx4 acc[2][4];

#define ZERO_ACC() do { \
  _Pragma("unroll") for (int rt = 0; rt < 2; ++rt) \
  _Pragma("unroll") for (int ct = 0; ct < 4; ++ct) acc[rt][ct] = (floatx4)(0.f); } while (0)

  // Pipelined stage: S k-steps; B from fragment stream, A from LDS; ping-pong regs.
#define STAGE(S, AH, AL, ASTR, BH, BL) do { \
  bf16x8 ah[2][2], al[2][2], bh[2][4], bl[2][4]; \
  _Pragma("unroll") for (int ct = 0; ct < 4; ++ct) { \
    bh[0][ct] = *(const bf16x8*)((BH) + (size_t)((wave * 4 + ct) * 64 + lane) * 8); \
    bl[0][ct] = *(const bf16x8*)((BL) + (size_t)((wave * 4 + ct) * 64 + lane) * 8); } \
  _Pragma("unroll") for (int rt = 0; rt < 2; ++rt) { \
    ah[0][rt] = *(const bf16x8*)(&(AH)[(rt * 16 + l16) * (ASTR) + quad * 8]); \
    al[0][rt] = *(const bf16x8*)(&(AL)[(rt * 16 + l16) * (ASTR) + quad * 8]); } \
  _Pragma("unroll") \
  for (int s = 0; s < (S); ++s) { \
    int cur = s & 1, nxt = cur ^ 1; \
    if (s + 1 < (S)) { \
      _Pragma("unroll") for (int ct = 0; ct < 4; ++ct) { \
        bh[nxt][ct] = *(const bf16x8*)((BH) + (size_t)(((s + 1) * 16 + wave * 4 + ct) * 64 + lane) * 8); \
        bl[nxt][ct] = *(const bf16x8*)((BL) + (size_t)(((s + 1) * 16 + wave * 4 + ct) * 64 + lane) * 8); } \
      _Pragma("unroll") for (int rt = 0; rt < 2; ++rt) { \
        ah[nxt][rt] = *(const bf16x8*)(&(AH)[(rt * 16 + l16) * (ASTR) + (s + 1) * 32 + quad * 8]); \
        al[nxt][rt] = *(const bf16x8*)(&(AL)[(rt * 16 + l16) * (ASTR) + (s + 1) * 32 + quad * 8]); } } \
    _Pragma("unroll") for (int rt = 0; rt < 2; ++rt) \
    _Pragma("unroll") for (int ct = 0; ct < 4; ++ct) { \
      acc[rt][ct] = __builtin_amdgcn_mfma_f32_16x16x32_bf16(ah[cur][rt], bh[cur][ct], acc[rt][ct], 0, 0, 0); \
      acc[rt][ct] = __builtin_amdgcn_mfma_f32_16x16x32_bf16(ah[cur][rt], bl[cur][ct], acc[rt][ct], 0, 0, 0); \
      acc[rt][ct] = __builtin_amdgcn_mfma_f32_16x16x32_bf16(al[cur][rt], bh[cur][ct], acc[rt][ct], 0, 0, 0); } \
  } } while (0)

  // ---- stage 1: H = ReLU(X @ W0 + b0), K=64 (padded)
  ZERO_ACC();
  STAGE(2, Xh, Xl, XSTR, F0h, F0l);
#pragma unroll
  for (int ct = 0; ct < 4; ++ct) {
    int col = wave * 64 + ct * 16 + l16;
    float bias = b0[col];
#pragma unroll
    for (int rt = 0; rt < 2; ++rt)
#pragma unroll
      for (int r = 0; r < 4; ++r) {
        int row = rt * 16 + quad * 4 + r;
        float h = fmaxf(acc[rt][ct][r] + bias, 0.f);
        split2(h, Hh[row * HSTR + col], Hl[row * HSTR + col]);
      }
  }
  __syncthreads();

  // ---- stage 2: E = ReLU(H @ W1 + b1), K=256
  ZERO_ACC();
  STAGE(8, Hh, Hl, HSTR, F1h, F1l);
  __syncthreads();  // all H reads done before overwriting region with E
#pragma unroll
  for (int ct = 0; ct < 4; ++ct) {
    int col = wave * 64 + ct * 16 + l16;
    float bias = b1[col];
#pragma unroll
    for (int rt = 0; rt < 2; ++rt)
#pragma unroll
      for (int r = 0; r < 4; ++r) {
        int row = rt * 16 + quad * 4 + r;
        float e = fmaxf(acc[rt][ct][r] + bias, 0.f);
        split2(e, Hh[row * HSTR + col], Hl[row * HSTR + col]);
      }
  }
  __syncthreads();

  // ---- stage 3: P = E @ W2 (rp_b folded into Q), K=256, fp32 out
  ZERO_ACC();
  STAGE(8, Hh, Hl, HSTR, F2h, F2l);
#pragma unroll
  for (int ct = 0; ct < 4; ++ct) {
    int col = wave * 64 + ct * 16 + l16;
#pragma unroll
    for (int rt = 0; rt < 2; ++rt)
#pragma unroll
      for (int r = 0; r < 4; ++r) {
        int row = rt * 16 + quad * 4 + r;
        P[(size_t)(row0 + row) * NF + col] = acc[rt][ct][r];
      }
  }
#undef ZERO_ACC
#undef STAGE
}

// ---------------------------------------------------------------------------
// fp32 16-row x 256-col tile GEMM helpers (small kernels)
// ---------------------------------------------------------------------------
__device__ __forceinline__ void gemm_acc(float acc[4][4],
    const float* Asm, int lda,
    const float* __restrict__ W, int K, int r0, int c0)
{
  for (int k = 0; k < K; k += 4) {
    float4 wa = *(const float4*)(W + (k + 0) * NF + c0);
    float4 wb = *(const float4*)(W + (k + 1) * NF + c0);
    float4 wc = *(const float4*)(W + (k + 2) * NF + c0);
    float4 wd = *(const float4*)(W + (k + 3) * NF + c0);
#pragma unroll
    for (int r = 0; r < 4; ++r) {
      float4 a = *(const float4*)(Asm + (r0 + r) * lda + k);
      acc[r][0] += a.x * wa.x + a.y * wb.x + a.z * wc.x + a.w * wd.x;
      acc[r][1] += a.x * wa.y + a.y * wb.y + a.z * wc.y + a.w * wd.y;
      acc[r][2] += a.x * wa.z + a.y * wb.z + a.z * wc.z + a.w * wd.z;
      acc[r][3] += a.x * wa.w + a.y * wb.w + a.z * wc.w + a.w * wd.w;
    }
  }
}

__device__ __forceinline__ void init_acc(float acc[4][4], const float* __restrict__ bias, int c0)
{
  if (bias) {
    float4 bb = *(const float4*)(bias + c0);
#pragma unroll
    for (int r = 0; r < 4; ++r) { acc[r][0] = bb.x; acc[r][1] = bb.y; acc[r][2] = bb.z; acc[r][3] = bb.w; }
  } else {
#pragma unroll
    for (int r = 0; r < 4; ++r) { acc[r][0] = 0.f; acc[r][1] = 0.f; acc[r][2] = 0.f; acc[r][3] = 0.f; }
  }
}

__device__ __forceinline__ void store_tile(float* dst, int ldd, float acc[4][4],
                                           int r0, int c0, bool relu)
{
#pragma unroll
  for (int r = 0; r < 4; ++r) {
    float4 v;
    v.x = relu ? fmaxf(acc[r][0], 0.f) : acc[r][0];
    v.y = relu ? fmaxf(acc[r][1], 0.f) : acc[r][1];
    v.z = relu ? fmaxf(acc[r][2], 0.f) : acc[r][2];
    v.w = relu ? fmaxf(acc[r][3], 0.f) : acc[r][3];
    *(float4*)(dst + (r0 + r) * ldd + c0) = v;
  }
}

__global__ __launch_bounds__(256) void enc_kernel(
    const float* __restrict__ attrs, const float* __restrict__ states,
    const float* __restrict__ w0, const float* __restrict__ b0,
    const float* __restrict__ w1, const float* __restrict__ b1,
    float* __restrict__ obj)
{
  __shared__ __align__(16) float X[16 * 20];
  __shared__ __align__(16) float H[16 * NF];
  int tid = threadIdx.x;
  int row0 = blockIdx.x * 16;
  for (int idx = tid; idx < 16 * 20; idx += 256) {
    int r = idx / 20, k = idx % 20;
    int m = row0 + r;
    X[idx] = (k < ATTR) ? attrs[m * ATTR + k] : states[m * STATE + (k - ATTR)];
  }
  __syncthreads();
  int c0 = (tid & 63) * 4, r0 = (tid >> 6) * 4;
  float acc[4][4];
  init_acc(acc, b0, c0);
  gemm_acc(acc, X, 20, w0, 20, r0, c0);
  store_tile(H, NF, acc, r0, c0, true);
  __syncthreads();
  init_acc(acc, b1, c0);
  gemm_acc(acc, H, NF, w1, NF, r0, c0);
  store_tile(obj + row0 * NF, NF, acc, r0, c0, true);
}

__global__ __launch_bounds__(256) void qr_kernel(
    const float* __restrict__ obj, const float* __restrict__ rpw,
    const float* __restrict__ rpb, float* __restrict__ Q, float* __restrict__ R)
{
  __shared__ __align__(16) float A[16 * NF];
  int tid = threadIdx.x;
  int row0 = blockIdx.x * 16;
  const float4* src = (const float4*)(obj + row0 * NF);
  float4* dst = (float4*)A;
  for (int i = tid; i < 16 * NF / 4; i += 256) dst[i] = src[i];
  __syncthreads();
  int c0 = (tid & 63) * 4, r0 = (tid >> 6) * 4;
  float acc[4][4];
  init_acc(acc, rpb, c0);
  gemm_acc(acc, A, NF, rpw + 256 * NF, NF, r0, c0);
  store_tile(Q + row0 * NF, NF, acc, r0, c0, false);
  init_acc(acc, nullptr, c0);
  gemm_acc(acc, A, NF, rpw + 512 * NF, NF, r0, c0);
  store_tile(R + row0 * NF, NF, acc, r0, c0, false);
}

// ---------------------------------------------------------------------------
// agg partials: part[jg][bi][c] = sum_{j in jg*8..+8} ReLU(P + Q_i + R_j)
// grid (1024, 8) -> 32 waves/CU; 8 independent loads per thread for ILP.
// HBM-bound on P (64 MB per pstep).
// ---------------------------------------------------------------------------
__global__ __launch_bounds__(256) void agg_part_kernel(
    const float* __restrict__ P, const float* __restrict__ Q,
    const float* __restrict__ R, float* __restrict__ part)
{
  int bi = blockIdx.x;
  int jg = blockIdx.y;
  int c = threadIdx.x;
  int b = bi >> 6;
  float q = Q[bi * NF + c];
  const float* Pr = P + ((size_t)bi * NN + jg * 8) * NF + c;
  const float* Rr = R + (b * NN + jg * 8) * NF + c;
  float s = 0.f;
#pragma unroll
  for (int j = 0; j < 8; ++j)
    s += fmaxf(Pr[j * NF] + q + Rr[j * NF], 0.f);
  part[((size_t)jg * NROWS_OBJ + bi) * NF + c] = s;
}

// ---------------------------------------------------------------------------
// obj_new = ReLU([obj, sum_jg part] @ pp_w + pp_b)  (agg combine folded in)
// ---------------------------------------------------------------------------
__global__ __launch_bounds__(256) void upd_kernel(
    const float* __restrict__ obj, const float* __restrict__ part,
    const float* __restrict__ ppw, const float* __restrict__ ppb,
    float* __restrict__ obj_out)
{
  __shared__ __align__(16) float A[16 * NF];
  __shared__ __align__(16) float Gs[16 * NF];
  int tid = threadIdx.x;
  int row0 = blockIdx.x * 16;
  {
    const float4* s1 = (const float4*)(obj + row0 * NF);
    float4* d1 = (float4*)A;
    float4* d2 = (float4*)Gs;
    for (int i = tid; i < 16 * NF / 4; i += 256) {
      d1[i] = s1[i];
      int r = i / (NF / 4), cc = i % (NF / 4);
      float4 s = make_float4(0.f, 0.f, 0.f, 0.f);
#pragma unroll
      for (int jg = 0; jg < 8; ++jg) {
        float4 p = ((const float4*)(part + ((size_t)jg * NROWS_OBJ + row0 + r) * NF))[cc];
        s.x += p.x; s.y += p.y; s.z += p.z; s.w += p.w;
      }
      d2[i] = s;
    }
  }
  __syncthreads();
  int c0 = (tid & 63) * 4, r0 = (tid >> 6) * 4;
  float acc[4][4];
  init_acc(acc, ppb, c0);
  gemm_acc(acc, A, NF, ppw, NF, r0, c0);
  gemm_acc(acc, Gs, NF, ppw + 256 * NF, NF, r0, c0);
  store_tile(obj_out + row0 * NF, NF, acc, r0, c0, true);
}

__global__ __launch_bounds__(256) void pred_kernel(
    const float* __restrict__ obj,
    const float* __restrict__ w0, const float* __restrict__ b0,
    const float* __restrict__ w1, const float* __restrict__ b1,
    float* __restrict__ out)
{
  __shared__ __align__(16) float A[16 * NF];
  __shared__ __align__(16) float T[16 * NF];
  int tid = threadIdx.x;
  int row0 = blockIdx.x * 16;
  {
    const float4* s1 = (const float4*)(obj + row0 * NF);
    float4* d1 = (float4*)A;
    for (int i = tid; i < 16 * NF / 4; i += 256) d1[i] = s1[i];
  }
  __syncthreads();
  int c0 = (tid & 63) * 4, r0 = (tid >> 6) * 4;
  float acc[4][4];
  init_acc(acc, b0, c0);
  gemm_acc(acc, A, NF, w0, NF, r0, c0);
  store_tile(T, NF, acc, r0, c0, true);
  __syncthreads();
  for (int idx = tid; idx < 16 * GG; idx += 256) {
    int r = idx >> 5, g = idx & 31;
    float a = b1[g];
    const float* Tr = T + r * NF;
    for (int k = 0; k < NF; ++k) a += Tr[k] * w1[k * GG + g];
    out[(row0 + r) * GG + g] = tanhf(a);
  }
}

extern "C" void kernel_launch(void* const* d_in, const int* in_sizes, int n_in,
                              void* d_out, int out_size, void* d_ws, size_t ws_size,
                              hipStream_t stream)
{
  const float* attrs     = (const float*)d_in[0];
  const float* states    = (const float*)d_in[1];
  const float* rel_attrs = (const float*)d_in[2];
  // d_in[3] = pstep (==2, structural)
  const float* enc_w0  = (const float*)d_in[4];
  const float* enc_b0  = (const float*)d_in[5];
  const float* enc_w1  = (const float*)d_in[6];
  const float* enc_b1  = (const float*)d_in[7];
  const float* rel_w0  = (const float*)d_in[8];
  const float* rel_b0  = (const float*)d_in[9];
  const float* rel_w1  = (const float*)d_in[10];
  const float* rel_b1  = (const float*)d_in[11];
  const float* rp_w    = (const float*)d_in[12];
  const float* rp_b    = (const float*)d_in[13];
  const float* pp_w    = (const float*)d_in[14];
  const float* pp_b    = (const float*)d_in[15];
  const float* pred_w0 = (const float*)d_in[16];
  const float* pred_b0 = (const float*)d_in[17];
  const float* pred_w1 = (const float*)d_in[18];
  const float* pred_b1 = (const float*)d_in[19];
  float* out = (float*)d_out;

  char* ws = (char*)d_ws;
  float* P    = (float*)ws;                                  // 64 MB
  float* obj0 = P + (size_t)NROWS_REL * NF;
  float* obj1 = obj0 + NROWS_OBJ * NF;
  float* Q    = obj1 + NROWS_OBJ * NF;
  float* R    = Q + NROWS_OBJ * NF;
  float* part = R + NROWS_OBJ * NF;                          // 8 * 1024 * 256 = 8 MB
  ushort_t* F0h = (ushort_t*)(part + 8 * (size_t)NROWS_OBJ * NF);
  ushort_t* F0l = F0h + F0_ELEMS;
  ushort_t* F1h = F0l + F0_ELEMS;
  ushort_t* F1l = F1h + F1_ELEMS;
  ushort_t* F2h = F1l + F1_ELEMS;
  ushort_t* F2l = F2h + F1_ELEMS;

  wprep_kernel<<<(F0_ELEMS + 2 * F1_ELEMS + 255) / 256, 256, 0, stream>>>(
      rel_w0, rel_w1, rp_w, F0h, F0l, F1h, F1l, F2h, F2l);
  enc_kernel<<<NROWS_OBJ / 16, 256, 0, stream>>>(attrs, states, enc_w0, enc_b0,
                                                 enc_w1, enc_b1, obj0);
  rel_chain_mfma<<<NROWS_REL / ROWS, 256, 0, stream>>>(attrs, states, rel_attrs,
                                                       F0h, F0l, rel_b0,
                                                       F1h, F1l, rel_b1,
                                                       F2h, F2l, P);
  float* cur = obj0; float* nxt = obj1;
  for (int p = 0; p < 2; ++p) {
    qr_kernel<<<NROWS_OBJ / 16, 256, 0, stream>>>(cur, rp_w, rp_b, Q, R);
    agg_part_kernel<<<dim3(NROWS_OBJ, 8), 256, 0, stream>>>(P, Q, R, part);
    upd_kernel<<<NROWS_OBJ / 16, 256, 0, stream>>>(cur, part, pp_w, pp_b, nxt);
    float* t = cur; cur = nxt; nxt = t;
  }
  pred_kernel<<<NROWS_OBJ / 16, 256, 0, stream>>>(cur, pred_w0, pred_b0,
                                                  pred_w1, pred_b1, out);
}

// Round 5
// 383.571 us; speedup vs baseline: 1.5970x; 1.0379x over previous
//
#include <hip/hip_runtime.h>
#include <hip/hip_bf16.h>
#include <math.h>

// Problem constants (fixed by reference setup_inputs)
#define BB 16
#define NN 64
#define ATTR 4
#define STATE 16
#define RELD 9
#define GG 32
#define NF 256
#define NROWS_OBJ (BB*NN)        // 1024
#define NROWS_REL (BB*NN*NN)     // 65536

typedef __bf16 bf16x8 __attribute__((ext_vector_type(8)));
typedef float  floatx4 __attribute__((ext_vector_type(4)));
typedef unsigned short ushort_t;

__device__ __forceinline__ ushort_t f2bf(float f) {
  unsigned int u = __float_as_uint(f);
  unsigned int r = (u + 0x7fffu + ((u >> 16) & 1u)) >> 16;
  return (ushort_t)r;
}
__device__ __forceinline__ float bf2f(ushort_t u) {
  return __uint_as_float(((unsigned int)u) << 16);
}
// bf16x3 split: x ~= h + l with |x-(h+l)| ~ 2^-18 |x|
__device__ __forceinline__ void split2(float x, ushort_t& h, ushort_t& l) {
  h = f2bf(x);
  float r = x - bf2f(h);
  l = f2bf(r);
}

// ---------------------------------------------------------------------------
// Weight prep: bf16x3 split weights in MFMA FRAGMENT-STREAM order:
//   F[((s*16 + g)*64 + lane)*8 + j] = W[k = s*32 + (lane>>4)*8 + j][n = g*16 + (lane&15)]
// so a wave's B-fragment load is base + lane*16B — one coalesced 1KB transaction.
// ---------------------------------------------------------------------------
#define F0_ELEMS (2 * 16 * 64 * 8)   // 16384
#define F1_ELEMS (8 * 16 * 64 * 8)   // 65536

__global__ __launch_bounds__(256) void wprep_kernel(
    const float* __restrict__ w0, const float* __restrict__ w1,
    const float* __restrict__ rpw,
    ushort_t* __restrict__ F0h, ushort_t* __restrict__ F0l,
    ushort_t* __restrict__ F1h, ushort_t* __restrict__ F1l,
    ushort_t* __restrict__ F2h, ushort_t* __restrict__ F2l)
{
  int idx = blockIdx.x * 256 + threadIdx.x;
  if (idx < F0_ELEMS) {
    int j = idx & 7, lane = (idx >> 3) & 63, g = (idx >> 9) & 15, s = idx >> 13;
    int k = s * 32 + (lane >> 4) * 8 + j, n = g * 16 + (lane & 15);
    float v = (k < 33) ? w0[k * NF + n] : 0.f;
    split2(v, F0h[idx], F0l[idx]);
    return;
  }
  int t = idx - F0_ELEMS;
  if (t < F1_ELEMS) {
    int j = t & 7, lane = (t >> 3) & 63, g = (t >> 9) & 15, s = t >> 13;
    int k = s * 32 + (lane >> 4) * 8 + j, n = g * 16 + (lane & 15);
    split2(w1[k * NF + n], F1h[t], F1l[t]);
    return;
  }
  t -= F1_ELEMS;
  if (t < F1_ELEMS) {
    int j = t & 7, lane = (t >> 3) & 63, g = (t >> 9) & 15, s = t >> 13;
    int k = s * 32 + (lane >> 4) * 8 + j, n = g * 16 + (lane & 15);
    split2(rpw[k * NF + n], F2h[t], F2l[t]);
  }
}

// ---------------------------------------------------------------------------
// Relation chain, bf16x3 split MFMA, software-pipelined.
// ROWS=48 per block (L2 weight traffic ∝ 1/ROWS: 1366 blocks * 576KB = 787MB).
// LDS 63KB: X split (48x72) + H split (48x264); E overwrites H after barrier.
// Wave w owns cols [64w,64w+64): 3x4 grid of 16x16 tiles, 36 MFMA/k-step.
// ---------------------------------------------------------------------------
#define ROWS 48
#define NRT 3
#define NBLK ((NROWS_REL + ROWS - 1) / ROWS)   // 1366
#define HSTR 264
#define XSTR 72

__global__ __launch_bounds__(256) void rel_chain_mfma(
    const float* __restrict__ attrs, const float* __restrict__ states,
    const float* __restrict__ rel_attrs,
    const ushort_t* __restrict__ F0h, const ushort_t* __restrict__ F0l,
    const float* __restrict__ b0,
    const ushort_t* __restrict__ F1h, const ushort_t* __restrict__ F1l,
    const float* __restrict__ b1,
    const ushort_t* __restrict__ F2h, const ushort_t* __restrict__ F2l,
    float* __restrict__ P)
{
  __shared__ __align__(16) ushort_t Hh[ROWS * HSTR];
  __shared__ __align__(16) ushort_t Hl[ROWS * HSTR];
  __shared__ __align__(16) ushort_t Xh[ROWS * XSTR];
  __shared__ __align__(16) ushort_t Xl[ROWS * XSTR];

  int tid  = threadIdx.x;
  int wave = tid >> 6;
  int lane = tid & 63;
  int quad = lane >> 4;
  int l16  = lane & 15;
  int row0 = blockIdx.x * ROWS;

  // Build X (48 rows x 33 cols, zero-padded to 64), split bf16; guard tail block
  for (int idx = tid; idx < ROWS * 64; idx += 256) {
    int r = idx >> 6, k = idx & 63;
    int grow = row0 + r;
    float v = 0.f;
    if (grow < NROWS_REL) {
      int j = grow & 63, i = (grow >> 6) & 63, b = grow >> 12;
      if (k < RELD)                     v = rel_attrs[(size_t)grow * RELD + k];
      else if (k < RELD + STATE)        v = states[(b * NN + i) * STATE + (k - RELD)]
                                          - states[(b * NN + j) * STATE + (k - RELD)];
      else if (k < RELD + STATE + ATTR) v = attrs[(b * NN + i) * ATTR + (k - RELD - STATE)];
      else if (k < 33)                  v = attrs[(b * NN + j) * ATTR + (k - RELD - STATE - ATTR)];
    }
    ushort_t h, l; split2(v, h, l);
    Xh[r * XSTR + k] = h;
    Xl[r * XSTR + k] = l;
  }
  __syncthreads();

  floatx4 acc[NRT][4];

#define ZERO_ACC() do { \
  _Pragma("unroll") for (int rt = 0; rt < NRT; ++rt) \
  _Pragma("unroll") for (int ct = 0; ct < 4; ++ct) acc[rt][ct] = (floatx4)(0.f); } while (0)

  // Pipelined stage: S k-steps; B from fragment stream, A from LDS; ping-pong regs.
#define STAGE(S, AH, AL, ASTR, BH, BL) do { \
  bf16x8 ah[2][NRT], al[2][NRT], bh[2][4], bl[2][4]; \
  _Pragma("unroll") for (int ct = 0; ct < 4; ++ct) { \
    bh[0][ct] = *(const bf16x8*)((BH) + (size_t)((wave * 4 + ct) * 64 + lane) * 8); \
    bl[0][ct] = *(const bf16x8*)((BL) + (size_t)((wave * 4 + ct) * 64 + lane) * 8); } \
  _Pragma("unroll") for (int rt = 0; rt < NRT; ++rt) { \
    ah[0][rt] = *(const bf16x8*)(&(AH)[(rt * 16 + l16) * (ASTR) + quad * 8]); \
    al[0][rt] = *(const bf16x8*)(&(AL)[(rt * 16 + l16) * (ASTR) + quad * 8]); } \
  _Pragma("unroll") \
  for (int s = 0; s < (S); ++s) { \
    int cur = s & 1, nxt = cur ^ 1; \
    if (s + 1 < (S)) { \
      _Pragma("unroll") for (int ct = 0; ct < 4; ++ct) { \
        bh[nxt][ct] = *(const bf16x8*)((BH) + (size_t)(((s + 1) * 16 + wave * 4 + ct) * 64 + lane) * 8); \
        bl[nxt][ct] = *(const bf16x8*)((BL) + (size_t)(((s + 1) * 16 + wave * 4 + ct) * 64 + lane) * 8); } \
      _Pragma("unroll") for (int rt = 0; rt < NRT; ++rt) { \
        ah[nxt][rt] = *(const bf16x8*)(&(AH)[(rt * 16 + l16) * (ASTR) + (s + 1) * 32 + quad * 8]); \
        al[nxt][rt] = *(const bf16x8*)(&(AL)[(rt * 16 + l16) * (ASTR) + (s + 1) * 32 + quad * 8]); } } \
    _Pragma("unroll") for (int rt = 0; rt < NRT; ++rt) \
    _Pragma("unroll") for (int ct = 0; ct < 4; ++ct) { \
      acc[rt][ct] = __builtin_amdgcn_mfma_f32_16x16x32_bf16(ah[cur][rt], bh[cur][ct], acc[rt][ct], 0, 0, 0); \
      acc[rt][ct] = __builtin_amdgcn_mfma_f32_16x16x32_bf16(ah[cur][rt], bl[cur][ct], acc[rt][ct], 0, 0, 0); \
      acc[rt][ct] = __builtin_amdgcn_mfma_f32_16x16x32_bf16(al[cur][rt], bh[cur][ct], acc[rt][ct], 0, 0, 0); } \
  } } while (0)

  // ---- stage 1: H = ReLU(X @ W0 + b0), K=64 (padded)
  ZERO_ACC();
  STAGE(2, Xh, Xl, XSTR, F0h, F0l);
#pragma unroll
  for (int ct = 0; ct < 4; ++ct) {
    int col = wave * 64 + ct * 16 + l16;
    float bias = b0[col];
#pragma unroll
    for (int rt = 0; rt < NRT; ++rt)
#pragma unroll
      for (int r = 0; r < 4; ++r) {
        int row = rt * 16 + quad * 4 + r;
        float h = fmaxf(acc[rt][ct][r] + bias, 0.f);
        split2(h, Hh[row * HSTR + col], Hl[row * HSTR + col]);
      }
  }
  __syncthreads();

  // ---- stage 2: E = ReLU(H @ W1 + b1), K=256
  ZERO_ACC();
  STAGE(8, Hh, Hl, HSTR, F1h, F1l);
  __syncthreads();  // all H reads done before overwriting region with E
#pragma unroll
  for (int ct = 0; ct < 4; ++ct) {
    int col = wave * 64 + ct * 16 + l16;
    float bias = b1[col];
#pragma unroll
    for (int rt = 0; rt < NRT; ++rt)
#pragma unroll
      for (int r = 0; r < 4; ++r) {
        int row = rt * 16 + quad * 4 + r;
        float e = fmaxf(acc[rt][ct][r] + bias, 0.f);
        split2(e, Hh[row * HSTR + col], Hl[row * HSTR + col]);
      }
  }
  __syncthreads();

  // ---- stage 3: P = E @ W2 (rp_b folded into Q), K=256, fp32 out
  ZERO_ACC();
  STAGE(8, Hh, Hl, HSTR, F2h, F2l);
#pragma unroll
  for (int ct = 0; ct < 4; ++ct) {
    int col = wave * 64 + ct * 16 + l16;
#pragma unroll
    for (int rt = 0; rt < NRT; ++rt)
#pragma unroll
      for (int r = 0; r < 4; ++r) {
        int row = rt * 16 + quad * 4 + r;
        if (row0 + row < NROWS_REL)
          P[(size_t)(row0 + row) * NF + col] = acc[rt][ct][r];
      }
  }
#undef ZERO_ACC
#undef STAGE
}

// ---------------------------------------------------------------------------
// fp32 16-row x 256-col tile GEMM helpers (small kernels)
// ---------------------------------------------------------------------------
__device__ __forceinline__ void gemm_acc(float acc[4][4],
    const float* Asm, int lda,
    const float* __restrict__ W, int K, int r0, int c0)
{
  for (int k = 0; k < K; k += 4) {
    float4 wa = *(const float4*)(W + (k + 0) * NF + c0);
    float4 wb = *(const float4*)(W + (k + 1) * NF + c0);
    float4 wc = *(const float4*)(W + (k + 2) * NF + c0);
    float4 wd = *(const float4*)(W + (k + 3) * NF + c0);
#pragma unroll
    for (int r = 0; r < 4; ++r) {
      float4 a = *(const float4*)(Asm + (r0 + r) * lda + k);
      acc[r][0] += a.x * wa.x + a.y * wb.x + a.z * wc.x + a.w * wd.x;
      acc[r][1] += a.x * wa.y + a.y * wb.y + a.z * wc.y + a.w * wd.y;
      acc[r][2] += a.x * wa.z + a.y * wb.z + a.z * wc.z + a.w * wd.z;
      acc[r][3] += a.x * wa.w + a.y * wb.w + a.z * wc.w + a.w * wd.w;
    }
  }
}

__device__ __forceinline__ void init_acc(float acc[4][4], const float* __restrict__ bias, int c0)
{
  if (bias) {
    float4 bb = *(const float4*)(bias + c0);
#pragma unroll
    for (int r = 0; r < 4; ++r) { acc[r][0] = bb.x; acc[r][1] = bb.y; acc[r][2] = bb.z; acc[r][3] = bb.w; }
  } else {
#pragma unroll
    for (int r = 0; r < 4; ++r) { acc[r][0] = 0.f; acc[r][1] = 0.f; acc[r][2] = 0.f; acc[r][3] = 0.f; }
  }
}

__device__ __forceinline__ void store_tile(float* dst, int ldd, float acc[4][4],
                                           int r0, int c0, bool relu)
{
#pragma unroll
  for (int r = 0; r < 4; ++r) {
    float4 v;
    v.x = relu ? fmaxf(acc[r][0], 0.f) : acc[r][0];
    v.y = relu ? fmaxf(acc[r][1], 0.f) : acc[r][1];
    v.z = relu ? fmaxf(acc[r][2], 0.f) : acc[r][2];
    v.w = relu ? fmaxf(acc[r][3], 0.f) : acc[r][3];
    *(float4*)(dst + (r0 + r) * ldd + c0) = v;
  }
}

// ---------------------------------------------------------------------------
// Fused encoder + Q/R: obj = ReLU(ReLU(X@w0+b0)@w1+b1); Q = obj@rpw[256:512]+rpb;
// R = obj@rpw[512:768]. obj stays in LDS for the Q/R GEMMs.
// ---------------------------------------------------------------------------
__global__ __launch_bounds__(256) void enc_qr_kernel(
    const float* __restrict__ attrs, const float* __restrict__ states,
    const float* __restrict__ w0, const float* __restrict__ b0,
    const float* __restrict__ w1, const float* __restrict__ b1,
    const float* __restrict__ rpw, const float* __restrict__ rpb,
    float* __restrict__ obj, float* __restrict__ Q, float* __restrict__ R)
{
  __shared__ __align__(16) float X[16 * 20];
  __shared__ __align__(16) float H[16 * NF];
  __shared__ __align__(16) float O[16 * NF];
  int tid = threadIdx.x;
  int row0 = blockIdx.x * 16;
  for (int idx = tid; idx < 16 * 20; idx += 256) {
    int r = idx / 20, k = idx % 20;
    int m = row0 + r;
    X[idx] = (k < ATTR) ? attrs[m * ATTR + k] : states[m * STATE + (k - ATTR)];
  }
  __syncthreads();
  int c0 = (tid & 63) * 4, r0 = (tid >> 6) * 4;
  float acc[4][4];
  init_acc(acc, b0, c0);
  gemm_acc(acc, X, 20, w0, 20, r0, c0);
  store_tile(H, NF, acc, r0, c0, true);
  __syncthreads();
  init_acc(acc, b1, c0);
  gemm_acc(acc, H, NF, w1, NF, r0, c0);
  store_tile(O, NF, acc, r0, c0, true);
  store_tile(obj + row0 * NF, NF, acc, r0, c0, true);
  __syncthreads();
  init_acc(acc, rpb, c0);
  gemm_acc(acc, O, NF, rpw + 256 * NF, NF, r0, c0);
  store_tile(Q + row0 * NF, NF, acc, r0, c0, false);
  init_acc(acc, nullptr, c0);
  gemm_acc(acc, O, NF, rpw + 512 * NF, NF, r0, c0);
  store_tile(R + row0 * NF, NF, acc, r0, c0, false);
}

// ---------------------------------------------------------------------------
// agg partials: part[jg][bi][c] = sum_{j in jg*8..+8} ReLU(P + Q_i + R_j)
// grid (1024, 8); coalesced P stream.
// ---------------------------------------------------------------------------
__global__ __launch_bounds__(256) void agg_part_kernel(
    const float* __restrict__ P, const float* __restrict__ Q,
    const float* __restrict__ R, float* __restrict__ part)
{
  int bi = blockIdx.x;
  int jg = blockIdx.y;
  int c = threadIdx.x;
  int b = bi >> 6;
  float q = Q[bi * NF + c];
  const float* Pr = P + ((size_t)bi * NN + jg * 8) * NF + c;
  const float* Rr = R + (b * NN + jg * 8) * NF + c;
  float s = 0.f;
#pragma unroll
  for (int j = 0; j < 8; ++j)
    s += fmaxf(Pr[j * NF] + q + Rr[j * NF], 0.f);
  part[((size_t)jg * NROWS_OBJ + bi) * NF + c] = s;
}

// ---------------------------------------------------------------------------
// Fused update + Q/R: obj' = ReLU([obj, Σ part]@pp_w+pp_b); then Q',R' from obj'.
// ---------------------------------------------------------------------------
__global__ __launch_bounds__(256) void upd_qr_kernel(
    const float* __restrict__ obj, const float* __restrict__ part,
    const float* __restrict__ ppw, const float* __restrict__ ppb,
    const float* __restrict__ rpw, const float* __restrict__ rpb,
    float* __restrict__ obj_out, float* __restrict__ Q, float* __restrict__ R)
{
  __shared__ __align__(16) float A[16 * NF];
  __shared__ __align__(16) float Gs[16 * NF];
  int tid = threadIdx.x;
  int row0 = blockIdx.x * 16;
  {
    const float4* s1 = (const float4*)(obj + row0 * NF);
    float4* d1 = (float4*)A;
    float4* d2 = (float4*)Gs;
    for (int i = tid; i < 16 * NF / 4; i += 256) {
      d1[i] = s1[i];
      int r = i / (NF / 4), cc = i % (NF / 4);
      float4 s = make_float4(0.f, 0.f, 0.f, 0.f);
#pragma unroll
      for (int jg = 0; jg < 8; ++jg) {
        float4 p = ((const float4*)(part + ((size_t)jg * NROWS_OBJ + row0 + r) * NF))[cc];
        s.x += p.x; s.y += p.y; s.z += p.z; s.w += p.w;
      }
      d2[i] = s;
    }
  }
  __syncthreads();
  int c0 = (tid & 63) * 4, r0 = (tid >> 6) * 4;
  float acc[4][4];
  init_acc(acc, ppb, c0);
  gemm_acc(acc, A, NF, ppw, NF, r0, c0);
  gemm_acc(acc, Gs, NF, ppw + 256 * NF, NF, r0, c0);
  __syncthreads();                               // all reads of old A done
  store_tile(A, NF, acc, r0, c0, true);          // obj' -> LDS
  store_tile(obj_out + row0 * NF, NF, acc, r0, c0, true);
  __syncthreads();
  init_acc(acc, rpb, c0);
  gemm_acc(acc, A, NF, rpw + 256 * NF, NF, r0, c0);
  store_tile(Q + row0 * NF, NF, acc, r0, c0, false);
  init_acc(acc, nullptr, c0);
  gemm_acc(acc, A, NF, rpw + 512 * NF, NF, r0, c0);
  store_tile(R + row0 * NF, NF, acc, r0, c0, false);
}

// ---------------------------------------------------------------------------
// Fused final update + predictor: obj2 = ReLU([obj, Σ part]@pp_w+pp_b);
// out = tanh(ReLU(obj2@pred_w0+pred_b0)@pred_w1+pred_b1)
// ---------------------------------------------------------------------------
__global__ __launch_bounds__(256) void upd_pred_kernel(
    const float* __restrict__ obj, const float* __restrict__ part,
    const float* __restrict__ ppw, const float* __restrict__ ppb,
    const float* __restrict__ w0, const float* __restrict__ b0,
    const float* __restrict__ w1, const float* __restrict__ b1,
    float* __restrict__ out)
{
  __shared__ __align__(16) float A[16 * NF];
  __shared__ __align__(16) float Gs[16 * NF];
  int tid = threadIdx.x;
  int row0 = blockIdx.x * 16;
  {
    const float4* s1 = (const float4*)(obj + row0 * NF);
    float4* d1 = (float4*)A;
    float4* d2 = (float4*)Gs;
    for (int i = tid; i < 16 * NF / 4; i += 256) {
      d1[i] = s1[i];
      int r = i / (NF / 4), cc = i % (NF / 4);
      float4 s = make_float4(0.f, 0.f, 0.f, 0.f);
#pragma unroll
      for (int jg = 0; jg < 8; ++jg) {
        float4 p = ((const float4*)(part + ((size_t)jg * NROWS_OBJ + row0 + r) * NF))[cc];
        s.x += p.x; s.y += p.y; s.z += p.z; s.w += p.w;
      }
      d2[i] = s;
    }
  }
  __syncthreads();
  int c0 = (tid & 63) * 4, r0 = (tid >> 6) * 4;
  float acc[4][4];
  init_acc(acc, ppb, c0);
  gemm_acc(acc, A, NF, ppw, NF, r0, c0);
  gemm_acc(acc, Gs, NF, ppw + 256 * NF, NF, r0, c0);
  __syncthreads();
  store_tile(A, NF, acc, r0, c0, true);          // obj2 -> LDS (A)
  __syncthreads();
  init_acc(acc, b0, c0);
  gemm_acc(acc, A, NF, w0, NF, r0, c0);
  __syncthreads();                               // Gs reads done (first gemm)
  store_tile(Gs, NF, acc, r0, c0, true);         // T -> LDS (Gs)
  __syncthreads();
  for (int idx = tid; idx < 16 * GG; idx += 256) {
    int r = idx >> 5, g = idx & 31;
    float a = b1[g];
    const float* Tr = Gs + r * NF;
    for (int k = 0; k < NF; ++k) a += Tr[k] * w1[k * GG + g];
    out[(row0 + r) * GG + g] = tanhf(a);
  }
}

extern "C" void kernel_launch(void* const* d_in, const int* in_sizes, int n_in,
                              void* d_out, int out_size, void* d_ws, size_t ws_size,
                              hipStream_t stream)
{
  const float* attrs     = (const float*)d_in[0];
  const float* states    = (const float*)d_in[1];
  const float* rel_attrs = (const float*)d_in[2];
  // d_in[3] = pstep (==2, structural)
  const float* enc_w0  = (const float*)d_in[4];
  const float* enc_b0  = (const float*)d_in[5];
  const float* enc_w1  = (const float*)d_in[6];
  const float* enc_b1  = (const float*)d_in[7];
  const float* rel_w0  = (const float*)d_in[8];
  const float* rel_b0  = (const float*)d_in[9];
  const float* rel_w1  = (const float*)d_in[10];
  const float* rel_b1  = (const float*)d_in[11];
  const float* rp_w    = (const float*)d_in[12];
  const float* rp_b    = (const float*)d_in[13];
  const float* pp_w    = (const float*)d_in[14];
  const float* pp_b    = (const float*)d_in[15];
  const float* pred_w0 = (const float*)d_in[16];
  const float* pred_b0 = (const float*)d_in[17];
  const float* pred_w1 = (const float*)d_in[18];
  const float* pred_b1 = (const float*)d_in[19];
  float* out = (float*)d_out;

  char* ws = (char*)d_ws;
  float* P    = (float*)ws;                                  // 64 MB
  float* obj0 = P + (size_t)NROWS_REL * NF;
  float* obj1 = obj0 + NROWS_OBJ * NF;
  float* Q    = obj1 + NROWS_OBJ * NF;
  float* R    = Q + NROWS_OBJ * NF;
  float* part = R + NROWS_OBJ * NF;                          // 8 MB
  ushort_t* F0h = (ushort_t*)(part + 8 * (size_t)NROWS_OBJ * NF);
  ushort_t* F0l = F0h + F0_ELEMS;
  ushort_t* F1h = F0l + F0_ELEMS;
  ushort_t* F1l = F1h + F1_ELEMS;
  ushort_t* F2h = F1l + F1_ELEMS;
  ushort_t* F2l = F2h + F1_ELEMS;

  wprep_kernel<<<(F0_ELEMS + 2 * F1_ELEMS + 255) / 256, 256, 0, stream>>>(
      rel_w0, rel_w1, rp_w, F0h, F0l, F1h, F1l, F2h, F2l);
  enc_qr_kernel<<<NROWS_OBJ / 16, 256, 0, stream>>>(attrs, states, enc_w0, enc_b0,
                                                    enc_w1, enc_b1, rp_w, rp_b,
                                                    obj0, Q, R);
  rel_chain_mfma<<<NBLK, 256, 0, stream>>>(attrs, states, rel_attrs,
                                           F0h, F0l, rel_b0,
                                           F1h, F1l, rel_b1,
                                           F2h, F2l, P);
  // pstep 1
  agg_part_kernel<<<dim3(NROWS_OBJ, 8), 256, 0, stream>>>(P, Q, R, part);
  upd_qr_kernel<<<NROWS_OBJ / 16, 256, 0, stream>>>(obj0, part, pp_w, pp_b,
                                                    rp_w, rp_b, obj1, Q, R);
  // pstep 2 (final, fused with predictor)
  agg_part_kernel<<<dim3(NROWS_OBJ, 8), 256, 0, stream>>>(P, Q, R, part);
  upd_pred_kernel<<<NROWS_OBJ / 16, 256, 0, stream>>>(obj1, part, pp_w, pp_b,
                                                      pred_w0, pred_b0,
                                                      pred_w1, pred_b1, out);
}

// Round 6
// 304.019 us; speedup vs baseline: 2.0148x; 1.2617x over previous
//
#include <hip/hip_runtime.h>
#include <hip/hip_bf16.h>
#include <math.h>

// Problem constants (fixed by reference setup_inputs)
#define BB 16
#define NN 64
#define ATTR 4
#define STATE 16
#define RELD 9
#define GG 32
#define NF 256
#define NROWS_OBJ (BB*NN)        // 1024
#define NROWS_REL (BB*NN*NN)     // 65536

typedef __bf16 bf16x8 __attribute__((ext_vector_type(8)));
typedef float  floatx4 __attribute__((ext_vector_type(4)));
typedef unsigned short ushort_t;

__device__ __forceinline__ ushort_t f2bf(float f) {
  unsigned int u = __float_as_uint(f);
  unsigned int r = (u + 0x7fffu + ((u >> 16) & 1u)) >> 16;
  return (ushort_t)r;
}
__device__ __forceinline__ float bf2f(ushort_t u) {
  return __uint_as_float(((unsigned int)u) << 16);
}
// bf16x3 split: x ~= h + l with |x-(h+l)| ~ 2^-18 |x|
__device__ __forceinline__ void split2(float x, ushort_t& h, ushort_t& l) {
  h = f2bf(x);
  float r = x - bf2f(h);
  l = f2bf(r);
}

// ---------------------------------------------------------------------------
// Weight prep: bf16x3 split weights in MFMA FRAGMENT-STREAM order:
//   F[((s*16 + g)*64 + lane)*8 + j] = W[k = s*32 + (lane>>4)*8 + j][n = g*16 + (lane&15)]
// so a wave's B-fragment load is base + lane*16B — one coalesced 1KB transaction.
// ---------------------------------------------------------------------------
#define F0_ELEMS (2 * 16 * 64 * 8)   // 16384
#define F1_ELEMS (8 * 16 * 64 * 8)   // 65536

__global__ __launch_bounds__(256) void wprep_kernel(
    const float* __restrict__ w0, const float* __restrict__ w1,
    const float* __restrict__ rpw,
    ushort_t* __restrict__ F0h, ushort_t* __restrict__ F0l,
    ushort_t* __restrict__ F1h, ushort_t* __restrict__ F1l,
    ushort_t* __restrict__ F2h, ushort_t* __restrict__ F2l)
{
  int idx = blockIdx.x * 256 + threadIdx.x;
  if (idx < F0_ELEMS) {
    int j = idx & 7, lane = (idx >> 3) & 63, g = (idx >> 9) & 15, s = idx >> 13;
    int k = s * 32 + (lane >> 4) * 8 + j, n = g * 16 + (lane & 15);
    float v = (k < 33) ? w0[k * NF + n] : 0.f;
    split2(v, F0h[idx], F0l[idx]);
    return;
  }
  int t = idx - F0_ELEMS;
  if (t < F1_ELEMS) {
    int j = t & 7, lane = (t >> 3) & 63, g = (t >> 9) & 15, s = t >> 13;
    int k = s * 32 + (lane >> 4) * 8 + j, n = g * 16 + (lane & 15);
    split2(w1[k * NF + n], F1h[t], F1l[t]);
    return;
  }
  t -= F1_ELEMS;
  if (t < F1_ELEMS) {
    int j = t & 7, lane = (t >> 3) & 63, g = (t >> 9) & 15, s = t >> 13;
    int k = s * 32 + (lane >> 4) * 8 + j, n = g * 16 + (lane & 15);
    split2(rpw[k * NF + n], F2h[t], F2l[t]);
  }
}

// ---------------------------------------------------------------------------
// Relation chain, bf16x3 split MFMA, software-pipelined.
// ROWS=32, X buffers ALIASED onto H buffers (X dead after stage 1) ->
// LDS 33.8KB -> 4 blocks/CU = 16 waves/CU (R4 lesson: occupancy > L2 bytes).
// Wave w owns cols [64w,64w+64): 2x4 grid of 16x16 tiles, 24 MFMA/k-step.
// ---------------------------------------------------------------------------
#define ROWS 32
#define NRT 2
#define HSTR 264
#define XSTR 72

__global__ __launch_bounds__(256, 4) void rel_chain_mfma(
    const float* __restrict__ attrs, const float* __restrict__ states,
    const float* __restrict__ rel_attrs,
    const ushort_t* __restrict__ F0h, const ushort_t* __restrict__ F0l,
    const float* __restrict__ b0,
    const ushort_t* __restrict__ F1h, const ushort_t* __restrict__ F1l,
    const float* __restrict__ b1,
    const ushort_t* __restrict__ F2h, const ushort_t* __restrict__ F2l,
    float* __restrict__ P)
{
  __shared__ __align__(16) ushort_t Hh[ROWS * HSTR];
  __shared__ __align__(16) ushort_t Hl[ROWS * HSTR];
  // X aliased onto H region (2304 ushorts used of 8448; H written only after
  // a barrier that follows all X reads)
  ushort_t* Xh = Hh;
  ushort_t* Xl = Hl;

  int tid  = threadIdx.x;
  int wave = tid >> 6;
  int lane = tid & 63;
  int quad = lane >> 4;
  int l16  = lane & 15;
  int row0 = blockIdx.x * ROWS;

  // Build X (32 rows x 33 cols, zero-padded to 64), split bf16
  for (int idx = tid; idx < ROWS * 64; idx += 256) {
    int r = idx >> 6, k = idx & 63;
    int grow = row0 + r;
    int j = grow & 63, i = (grow >> 6) & 63, b = grow >> 12;
    float v = 0.f;
    if (k < RELD)                     v = rel_attrs[(size_t)grow * RELD + k];
    else if (k < RELD + STATE)        v = states[(b * NN + i) * STATE + (k - RELD)]
                                        - states[(b * NN + j) * STATE + (k - RELD)];
    else if (k < RELD + STATE + ATTR) v = attrs[(b * NN + i) * ATTR + (k - RELD - STATE)];
    else if (k < 33)                  v = attrs[(b * NN + j) * ATTR + (k - RELD - STATE - ATTR)];
    ushort_t h, l; split2(v, h, l);
    Xh[r * XSTR + k] = h;
    Xl[r * XSTR + k] = l;
  }
  __syncthreads();

  floatx4 acc[NRT][4];

#define ZERO_ACC() do { \
  _Pragma("unroll") for (int rt = 0; rt < NRT; ++rt) \
  _Pragma("unroll") for (int ct = 0; ct < 4; ++ct) acc[rt][ct] = (floatx4)(0.f); } while (0)

  // Pipelined stage: S k-steps; B from fragment stream, A from LDS; ping-pong regs.
#define STAGE(S, AH, AL, ASTR, BH, BL) do { \
  bf16x8 ah[2][NRT], al[2][NRT], bh[2][4], bl[2][4]; \
  _Pragma("unroll") for (int ct = 0; ct < 4; ++ct) { \
    bh[0][ct] = *(const bf16x8*)((BH) + (size_t)((wave * 4 + ct) * 64 + lane) * 8); \
    bl[0][ct] = *(const bf16x8*)((BL) + (size_t)((wave * 4 + ct) * 64 + lane) * 8); } \
  _Pragma("unroll") for (int rt = 0; rt < NRT; ++rt) { \
    ah[0][rt] = *(const bf16x8*)(&(AH)[(rt * 16 + l16) * (ASTR) + quad * 8]); \
    al[0][rt] = *(const bf16x8*)(&(AL)[(rt * 16 + l16) * (ASTR) + quad * 8]); } \
  _Pragma("unroll") \
  for (int s = 0; s < (S); ++s) { \
    int cur = s & 1, nxt = cur ^ 1; \
    if (s + 1 < (S)) { \
      _Pragma("unroll") for (int ct = 0; ct < 4; ++ct) { \
        bh[nxt][ct] = *(const bf16x8*)((BH) + (size_t)(((s + 1) * 16 + wave * 4 + ct) * 64 + lane) * 8); \
        bl[nxt][ct] = *(const bf16x8*)((BL) + (size_t)(((s + 1) * 16 + wave * 4 + ct) * 64 + lane) * 8); } \
      _Pragma("unroll") for (int rt = 0; rt < NRT; ++rt) { \
        ah[nxt][rt] = *(const bf16x8*)(&(AH)[(rt * 16 + l16) * (ASTR) + (s + 1) * 32 + quad * 8]); \
        al[nxt][rt] = *(const bf16x8*)(&(AL)[(rt * 16 + l16) * (ASTR) + (s + 1) * 32 + quad * 8]); } } \
    _Pragma("unroll") for (int rt = 0; rt < NRT; ++rt) \
    _Pragma("unroll") for (int ct = 0; ct < 4; ++ct) { \
      acc[rt][ct] = __builtin_amdgcn_mfma_f32_16x16x32_bf16(ah[cur][rt], bh[cur][ct], acc[rt][ct], 0, 0, 0); \
      acc[rt][ct] = __builtin_amdgcn_mfma_f32_16x16x32_bf16(ah[cur][rt], bl[cur][ct], acc[rt][ct], 0, 0, 0); \
      acc[rt][ct] = __builtin_amdgcn_mfma_f32_16x16x32_bf16(al[cur][rt], bh[cur][ct], acc[rt][ct], 0, 0, 0); } \
  } } while (0)

  // ---- stage 1: H = ReLU(X @ W0 + b0), K=64 (padded)
  ZERO_ACC();
  STAGE(2, Xh, Xl, XSTR, F0h, F0l);
  __syncthreads();  // ALL waves' X reads done before H overwrites the X region
#pragma unroll
  for (int ct = 0; ct < 4; ++ct) {
    int col = wave * 64 + ct * 16 + l16;
    float bias = b0[col];
#pragma unroll
    for (int rt = 0; rt < NRT; ++rt)
#pragma unroll
      for (int r = 0; r < 4; ++r) {
        int row = rt * 16 + quad * 4 + r;
        float h = fmaxf(acc[rt][ct][r] + bias, 0.f);
        split2(h, Hh[row * HSTR + col], Hl[row * HSTR + col]);
      }
  }
  __syncthreads();

  // ---- stage 2: E = ReLU(H @ W1 + b1), K=256
  ZERO_ACC();
  STAGE(8, Hh, Hl, HSTR, F1h, F1l);
  __syncthreads();  // all H reads done before overwriting region with E
#pragma unroll
  for (int ct = 0; ct < 4; ++ct) {
    int col = wave * 64 + ct * 16 + l16;
    float bias = b1[col];
#pragma unroll
    for (int rt = 0; rt < NRT; ++rt)
#pragma unroll
      for (int r = 0; r < 4; ++r) {
        int row = rt * 16 + quad * 4 + r;
        float e = fmaxf(acc[rt][ct][r] + bias, 0.f);
        split2(e, Hh[row * HSTR + col], Hl[row * HSTR + col]);
      }
  }
  __syncthreads();

  // ---- stage 3: P = E @ W2 (rp_b folded into Q), K=256, fp32 out
  ZERO_ACC();
  STAGE(8, Hh, Hl, HSTR, F2h, F2l);
#pragma unroll
  for (int ct = 0; ct < 4; ++ct) {
    int col = wave * 64 + ct * 16 + l16;
#pragma unroll
    for (int rt = 0; rt < NRT; ++rt)
#pragma unroll
      for (int r = 0; r < 4; ++r) {
        int row = rt * 16 + quad * 4 + r;
        P[(size_t)(row0 + row) * NF + col] = acc[rt][ct][r];
      }
  }
#undef ZERO_ACC
#undef STAGE
}

// ---------------------------------------------------------------------------
// Tail kernels: 4-row tiles, grid 256 blocks (1 block/CU), thread = 1 column.
// W loads coalesced (256 B/wave/k), independent across k -> compiler pipelines.
// ---------------------------------------------------------------------------

// Fused encoder + Q/R. obj = ReLU(ReLU(X@w0+b0)@w1+b1); Q,R from obj (in LDS).
__global__ __launch_bounds__(256) void enc_qr_kernel(
    const float* __restrict__ attrs, const float* __restrict__ states,
    const float* __restrict__ w0, const float* __restrict__ b0,
    const float* __restrict__ w1, const float* __restrict__ b1,
    const float* __restrict__ rpw, const float* __restrict__ rpb,
    float* __restrict__ obj, float* __restrict__ Q, float* __restrict__ R)
{
  __shared__ float X[4 * 20];
  __shared__ float H[4 * NF];
  __shared__ float O[4 * NF];
  int tid = threadIdx.x;
  int row0 = blockIdx.x * 4;
  if (tid < 80) {
    int r = tid / 20, k = tid % 20;
    int m = row0 + r;
    X[tid] = (k < ATTR) ? attrs[m * ATTR + k] : states[m * STATE + (k - ATTR)];
  }
  __syncthreads();
  int c = tid;
  float a0, a1, a2, a3;
  // stage 1: K=20
  a0 = a1 = a2 = a3 = b0[c];
#pragma unroll
  for (int k = 0; k < 20; ++k) {
    float w = w0[k * NF + c];
    a0 += X[0 * 20 + k] * w; a1 += X[1 * 20 + k] * w;
    a2 += X[2 * 20 + k] * w; a3 += X[3 * 20 + k] * w;
  }
  H[0 * NF + c] = fmaxf(a0, 0.f); H[1 * NF + c] = fmaxf(a1, 0.f);
  H[2 * NF + c] = fmaxf(a2, 0.f); H[3 * NF + c] = fmaxf(a3, 0.f);
  __syncthreads();
  // stage 2: K=256
  a0 = a1 = a2 = a3 = b1[c];
#pragma unroll 8
  for (int k = 0; k < NF; ++k) {
    float w = w1[k * NF + c];
    a0 += H[0 * NF + k] * w; a1 += H[1 * NF + k] * w;
    a2 += H[2 * NF + k] * w; a3 += H[3 * NF + k] * w;
  }
  a0 = fmaxf(a0, 0.f); a1 = fmaxf(a1, 0.f); a2 = fmaxf(a2, 0.f); a3 = fmaxf(a3, 0.f);
  O[0 * NF + c] = a0; O[1 * NF + c] = a1; O[2 * NF + c] = a2; O[3 * NF + c] = a3;
  obj[(row0 + 0) * NF + c] = a0; obj[(row0 + 1) * NF + c] = a1;
  obj[(row0 + 2) * NF + c] = a2; obj[(row0 + 3) * NF + c] = a3;
  __syncthreads();
  // Q = O @ rpw[256:512] + rpb
  a0 = a1 = a2 = a3 = rpb[c];
#pragma unroll 8
  for (int k = 0; k < NF; ++k) {
    float w = rpw[(256 + k) * NF + c];
    a0 += O[0 * NF + k] * w; a1 += O[1 * NF + k] * w;
    a2 += O[2 * NF + k] * w; a3 += O[3 * NF + k] * w;
  }
  Q[(row0 + 0) * NF + c] = a0; Q[(row0 + 1) * NF + c] = a1;
  Q[(row0 + 2) * NF + c] = a2; Q[(row0 + 3) * NF + c] = a3;
  // R = O @ rpw[512:768]
  a0 = a1 = a2 = a3 = 0.f;
#pragma unroll 8
  for (int k = 0; k < NF; ++k) {
    float w = rpw[(512 + k) * NF + c];
    a0 += O[0 * NF + k] * w; a1 += O[1 * NF + k] * w;
    a2 += O[2 * NF + k] * w; a3 += O[3 * NF + k] * w;
  }
  R[(row0 + 0) * NF + c] = a0; R[(row0 + 1) * NF + c] = a1;
  R[(row0 + 2) * NF + c] = a2; R[(row0 + 3) * NF + c] = a3;
}

// agg partials: part[jg][bi][c] = sum_{j in jg*8..+8} ReLU(P + Q_i + R_j)
__global__ __launch_bounds__(256) void agg_part_kernel(
    const float* __restrict__ P, const float* __restrict__ Q,
    const float* __restrict__ R, float* __restrict__ part)
{
  int bi = blockIdx.x;
  int jg = blockIdx.y;
  int c = threadIdx.x;
  int b = bi >> 6;
  float q = Q[bi * NF + c];
  const float* Pr = P + ((size_t)bi * NN + jg * 8) * NF + c;
  const float* Rr = R + (b * NN + jg * 8) * NF + c;
  float s = 0.f;
#pragma unroll
  for (int j = 0; j < 8; ++j)
    s += fmaxf(Pr[j * NF] + q + Rr[j * NF], 0.f);
  part[((size_t)jg * NROWS_OBJ + bi) * NF + c] = s;
}

// Fused update + Q/R: obj' = ReLU([obj, Σ part]@pp_w+pp_b); Q',R' from obj'.
__global__ __launch_bounds__(256) void upd_qr_kernel(
    const float* __restrict__ obj, const float* __restrict__ part,
    const float* __restrict__ ppw, const float* __restrict__ ppb,
    const float* __restrict__ rpw, const float* __restrict__ rpb,
    float* __restrict__ obj_out, float* __restrict__ Q, float* __restrict__ R)
{
  __shared__ float A[4 * NF];
  __shared__ float G[4 * NF];
  int tid = threadIdx.x;
  int row0 = blockIdx.x * 4;
  int c = tid;
#pragma unroll
  for (int r = 0; r < 4; ++r) {
    A[r * NF + c] = obj[(row0 + r) * NF + c];
    float s = 0.f;
#pragma unroll
    for (int jg = 0; jg < 8; ++jg)
      s += part[((size_t)jg * NROWS_OBJ + row0 + r) * NF + c];
    G[r * NF + c] = s;
  }
  __syncthreads();
  float a0, a1, a2, a3;
  a0 = a1 = a2 = a3 = ppb[c];
#pragma unroll 8
  for (int k = 0; k < NF; ++k) {
    float w = ppw[k * NF + c];
    a0 += A[0 * NF + k] * w; a1 += A[1 * NF + k] * w;
    a2 += A[2 * NF + k] * w; a3 += A[3 * NF + k] * w;
  }
#pragma unroll 8
  for (int k = 0; k < NF; ++k) {
    float w = ppw[(NF + k) * NF + c];
    a0 += G[0 * NF + k] * w; a1 += G[1 * NF + k] * w;
    a2 += G[2 * NF + k] * w; a3 += G[3 * NF + k] * w;
  }
  a0 = fmaxf(a0, 0.f); a1 = fmaxf(a1, 0.f); a2 = fmaxf(a2, 0.f); a3 = fmaxf(a3, 0.f);
  __syncthreads();                 // all reads of old A done
  A[0 * NF + c] = a0; A[1 * NF + c] = a1; A[2 * NF + c] = a2; A[3 * NF + c] = a3;
  obj_out[(row0 + 0) * NF + c] = a0; obj_out[(row0 + 1) * NF + c] = a1;
  obj_out[(row0 + 2) * NF + c] = a2; obj_out[(row0 + 3) * NF + c] = a3;
  __syncthreads();
  a0 = a1 = a2 = a3 = rpb[c];
#pragma unroll 8
  for (int k = 0; k < NF; ++k) {
    float w = rpw[(256 + k) * NF + c];
    a0 += A[0 * NF + k] * w; a1 += A[1 * NF + k] * w;
    a2 += A[2 * NF + k] * w; a3 += A[3 * NF + k] * w;
  }
  Q[(row0 + 0) * NF + c] = a0; Q[(row0 + 1) * NF + c] = a1;
  Q[(row0 + 2) * NF + c] = a2; Q[(row0 + 3) * NF + c] = a3;
  a0 = a1 = a2 = a3 = 0.f;
#pragma unroll 8
  for (int k = 0; k < NF; ++k) {
    float w = rpw[(512 + k) * NF + c];
    a0 += A[0 * NF + k] * w; a1 += A[1 * NF + k] * w;
    a2 += A[2 * NF + k] * w; a3 += A[3 * NF + k] * w;
  }
  R[(row0 + 0) * NF + c] = a0; R[(row0 + 1) * NF + c] = a1;
  R[(row0 + 2) * NF + c] = a2; R[(row0 + 3) * NF + c] = a3;
}

// Fused final update + predictor:
// obj2 = ReLU([obj, Σ part]@pp_w+pp_b); out = tanh(ReLU(obj2@w0+b0)@w1+b1)
__global__ __launch_bounds__(256) void upd_pred_kernel(
    const float* __restrict__ obj, const float* __restrict__ part,
    const float* __restrict__ ppw, const float* __restrict__ ppb,
    const float* __restrict__ w0, const float* __restrict__ b0,
    const float* __restrict__ w1, const float* __restrict__ b1,
    float* __restrict__ out)
{
  __shared__ float A[4 * NF];
  __shared__ float G[4 * NF];
  int tid = threadIdx.x;
  int row0 = blockIdx.x * 4;
  int c = tid;
#pragma unroll
  for (int r = 0; r < 4; ++r) {
    A[r * NF + c] = obj[(row0 + r) * NF + c];
    float s = 0.f;
#pragma unroll
    for (int jg = 0; jg < 8; ++jg)
      s += part[((size_t)jg * NROWS_OBJ + row0 + r) * NF + c];
    G[r * NF + c] = s;
  }
  __syncthreads();
  float a0, a1, a2, a3;
  a0 = a1 = a2 = a3 = ppb[c];
#pragma unroll 8
  for (int k = 0; k < NF; ++k) {
    float w = ppw[k * NF + c];
    a0 += A[0 * NF + k] * w; a1 += A[1 * NF + k] * w;
    a2 += A[2 * NF + k] * w; a3 += A[3 * NF + k] * w;
  }
#pragma unroll 8
  for (int k = 0; k < NF; ++k) {
    float w = ppw[(NF + k) * NF + c];
    a0 += G[0 * NF + k] * w; a1 += G[1 * NF + k] * w;
    a2 += G[2 * NF + k] * w; a3 += G[3 * NF + k] * w;
  }
  __syncthreads();                 // old A reads done
  A[0 * NF + c] = fmaxf(a0, 0.f); A[1 * NF + c] = fmaxf(a1, 0.f);
  A[2 * NF + c] = fmaxf(a2, 0.f); A[3 * NF + c] = fmaxf(a3, 0.f);
  __syncthreads();
  // T = ReLU(obj2 @ w0 + b0) -> G (G reads finished two barriers ago)
  a0 = a1 = a2 = a3 = b0[c];
#pragma unroll 8
  for (int k = 0; k < NF; ++k) {
    float w = w0[k * NF + c];
    a0 += A[0 * NF + k] * w; a1 += A[1 * NF + k] * w;
    a2 += A[2 * NF + k] * w; a3 += A[3 * NF + k] * w;
  }
  G[0 * NF + c] = fmaxf(a0, 0.f); G[1 * NF + c] = fmaxf(a1, 0.f);
  G[2 * NF + c] = fmaxf(a2, 0.f); G[3 * NF + c] = fmaxf(a3, 0.f);
  __syncthreads();
  if (tid < 4 * GG) {
    int r = tid >> 5, g = tid & 31;
    float a = b1[g];
    const float* Tr = G + r * NF;
#pragma unroll 8
    for (int k = 0; k < NF; ++k) a += Tr[k] * w1[k * GG + g];
    out[(row0 + r) * GG + g] = tanhf(a);
  }
}

extern "C" void kernel_launch(void* const* d_in, const int* in_sizes, int n_in,
                              void* d_out, int out_size, void* d_ws, size_t ws_size,
                              hipStream_t stream)
{
  const float* attrs     = (const float*)d_in[0];
  const float* states    = (const float*)d_in[1];
  const float* rel_attrs = (const float*)d_in[2];
  // d_in[3] = pstep (==2, structural)
  const float* enc_w0  = (const float*)d_in[4];
  const float* enc_b0  = (const float*)d_in[5];
  const float* enc_w1  = (const float*)d_in[6];
  const float* enc_b1  = (const float*)d_in[7];
  const float* rel_w0  = (const float*)d_in[8];
  const float* rel_b0  = (const float*)d_in[9];
  const float* rel_w1  = (const float*)d_in[10];
  const float* rel_b1  = (const float*)d_in[11];
  const float* rp_w    = (const float*)d_in[12];
  const float* rp_b    = (const float*)d_in[13];
  const float* pp_w    = (const float*)d_in[14];
  const float* pp_b    = (const float*)d_in[15];
  const float* pred_w0 = (const float*)d_in[16];
  const float* pred_b0 = (const float*)d_in[17];
  const float* pred_w1 = (const float*)d_in[18];
  const float* pred_b1 = (const float*)d_in[19];
  float* out = (float*)d_out;

  char* ws = (char*)d_ws;
  float* P    = (float*)ws;                                  // 64 MB
  float* obj0 = P + (size_t)NROWS_REL * NF;
  float* obj1 = obj0 + NROWS_OBJ * NF;
  float* Q    = obj1 + NROWS_OBJ * NF;
  float* R    = Q + NROWS_OBJ * NF;
  float* part = R + NROWS_OBJ * NF;                          // 8 MB
  ushort_t* F0h = (ushort_t*)(part + 8 * (size_t)NROWS_OBJ * NF);
  ushort_t* F0l = F0h + F0_ELEMS;
  ushort_t* F1h = F0l + F0_ELEMS;
  ushort_t* F1l = F1h + F1_ELEMS;
  ushort_t* F2h = F1l + F1_ELEMS;
  ushort_t* F2l = F2h + F1_ELEMS;

  wprep_kernel<<<(F0_ELEMS + 2 * F1_ELEMS + 255) / 256, 256, 0, stream>>>(
      rel_w0, rel_w1, rp_w, F0h, F0l, F1h, F1l, F2h, F2l);
  enc_qr_kernel<<<NROWS_OBJ / 4, 256, 0, stream>>>(attrs, states, enc_w0, enc_b0,
                                                   enc_w1, enc_b1, rp_w, rp_b,
                                                   obj0, Q, R);
  rel_chain_mfma<<<NROWS_REL / ROWS, 256, 0, stream>>>(attrs, states, rel_attrs,
                                                       F0h, F0l, rel_b0,
                                                       F1h, F1l, rel_b1,
                                                       F2h, F2l, P);
  // pstep 1
  agg_part_kernel<<<dim3(NROWS_OBJ, 8), 256, 0, stream>>>(P, Q, R, part);
  upd_qr_kernel<<<NROWS_OBJ / 4, 256, 0, stream>>>(obj0, part, pp_w, pp_b,
                                                   rp_w, rp_b, obj1, Q, R);
  // pstep 2 (final, fused with predictor)
  agg_part_kernel<<<dim3(NROWS_OBJ, 8), 256, 0, stream>>>(P, Q, R, part);
  upd_pred_kernel<<<NROWS_OBJ / 4, 256, 0, stream>>>(obj1, part, pp_w, pp_b,
                                                     pred_w0, pred_b0,
                                                     pred_w1, pred_b1, out);
}

// Round 7
// 293.240 us; speedup vs baseline: 2.0889x; 1.0368x over previous
//
#include <hip/hip_runtime.h>
#include <hip/hip_bf16.h>
#include <math.h>

// Problem constants (fixed by reference setup_inputs)
#define BB 16
#define NN 64
#define ATTR 4
#define STATE 16
#define RELD 9
#define GG 32
#define NF 256
#define NROWS_OBJ (BB*NN)        // 1024
#define NROWS_REL (BB*NN*NN)     // 65536

typedef __bf16 bf16x8 __attribute__((ext_vector_type(8)));
typedef float  floatx4 __attribute__((ext_vector_type(4)));
typedef unsigned short ushort_t;

__device__ __forceinline__ ushort_t f2bf(float f) {
  unsigned int u = __float_as_uint(f);
  unsigned int r = (u + 0x7fffu + ((u >> 16) & 1u)) >> 16;
  return (ushort_t)r;
}
__device__ __forceinline__ float bf2f(ushort_t u) {
  return __uint_as_float(((unsigned int)u) << 16);
}
// bf16x3 split: x ~= h + l with |x-(h+l)| ~ 2^-18 |x|
__device__ __forceinline__ void split2(float x, ushort_t& h, ushort_t& l) {
  h = f2bf(x);
  float r = x - bf2f(h);
  l = f2bf(r);
}

#define F0_ELEMS (2 * 16 * 64 * 8)   // 16384
#define F1_ELEMS (8 * 16 * 64 * 8)   // 65536
#define F_TOTAL  (F0_ELEMS + 2 * F1_ELEMS)

// ---------------------------------------------------------------------------
// Fused encoder + Q/R + weight-fragment prep (wprep folded in: independent
// work, saves one dispatch; rel_chain depends on F* via stream order).
// Fragment-stream layout: F[((s*16+g)*64+lane)*8+j] = W[k=s*32+(lane>>4)*8+j]
// [n=g*16+(lane&15)] -> B-fragment load is base + lane*16B, one 1KB txn.
// ---------------------------------------------------------------------------
__global__ __launch_bounds__(256) void enc_qr_prep_kernel(
    const float* __restrict__ attrs, const float* __restrict__ states,
    const float* __restrict__ w0, const float* __restrict__ b0,
    const float* __restrict__ w1, const float* __restrict__ b1,
    const float* __restrict__ rpw, const float* __restrict__ rpb,
    const float* __restrict__ rel_w0, const float* __restrict__ rel_w1,
    ushort_t* __restrict__ F0h, ushort_t* __restrict__ F0l,
    ushort_t* __restrict__ F1h, ushort_t* __restrict__ F1l,
    ushort_t* __restrict__ F2h, ushort_t* __restrict__ F2l,
    float* __restrict__ obj, float* __restrict__ Q, float* __restrict__ R)
{
  int tid = threadIdx.x;
  // ---- weight prep (grid-strided over all fragment elements)
  for (int idx = blockIdx.x * 256 + tid; idx < F_TOTAL; idx += 256 * 256) {
    if (idx < F0_ELEMS) {
      int j = idx & 7, lane = (idx >> 3) & 63, g = (idx >> 9) & 15, s = idx >> 13;
      int k = s * 32 + (lane >> 4) * 8 + j, n = g * 16 + (lane & 15);
      float v = (k < 33) ? rel_w0[k * NF + n] : 0.f;
      split2(v, F0h[idx], F0l[idx]);
    } else if (idx < F0_ELEMS + F1_ELEMS) {
      int t = idx - F0_ELEMS;
      int j = t & 7, lane = (t >> 3) & 63, g = (t >> 9) & 15, s = t >> 13;
      int k = s * 32 + (lane >> 4) * 8 + j, n = g * 16 + (lane & 15);
      split2(rel_w1[k * NF + n], F1h[t], F1l[t]);
    } else {
      int t = idx - (F0_ELEMS + F1_ELEMS);
      int j = t & 7, lane = (t >> 3) & 63, g = (t >> 9) & 15, s = t >> 13;
      int k = s * 32 + (lane >> 4) * 8 + j, n = g * 16 + (lane & 15);
      split2(rpw[k * NF + n], F2h[t], F2l[t]);
    }
  }
  // ---- encoder + Q/R (4 rows per block, thread = 1 column)
  __shared__ float X[4 * 20];
  __shared__ float H[4 * NF];
  __shared__ float O[4 * NF];
  int row0 = blockIdx.x * 4;
  if (tid < 80) {
    int r = tid / 20, k = tid % 20;
    int m = row0 + r;
    X[tid] = (k < ATTR) ? attrs[m * ATTR + k] : states[m * STATE + (k - ATTR)];
  }
  __syncthreads();
  int c = tid;
  float a0, a1, a2, a3;
  a0 = a1 = a2 = a3 = b0[c];
#pragma unroll
  for (int k = 0; k < 20; ++k) {
    float w = w0[k * NF + c];
    a0 += X[0 * 20 + k] * w; a1 += X[1 * 20 + k] * w;
    a2 += X[2 * 20 + k] * w; a3 += X[3 * 20 + k] * w;
  }
  H[0 * NF + c] = fmaxf(a0, 0.f); H[1 * NF + c] = fmaxf(a1, 0.f);
  H[2 * NF + c] = fmaxf(a2, 0.f); H[3 * NF + c] = fmaxf(a3, 0.f);
  __syncthreads();
  a0 = a1 = a2 = a3 = b1[c];
#pragma unroll 8
  for (int k = 0; k < NF; ++k) {
    float w = w1[k * NF + c];
    a0 += H[0 * NF + k] * w; a1 += H[1 * NF + k] * w;
    a2 += H[2 * NF + k] * w; a3 += H[3 * NF + k] * w;
  }
  a0 = fmaxf(a0, 0.f); a1 = fmaxf(a1, 0.f); a2 = fmaxf(a2, 0.f); a3 = fmaxf(a3, 0.f);
  O[0 * NF + c] = a0; O[1 * NF + c] = a1; O[2 * NF + c] = a2; O[3 * NF + c] = a3;
  obj[(row0 + 0) * NF + c] = a0; obj[(row0 + 1) * NF + c] = a1;
  obj[(row0 + 2) * NF + c] = a2; obj[(row0 + 3) * NF + c] = a3;
  __syncthreads();
  a0 = a1 = a2 = a3 = rpb[c];
#pragma unroll 8
  for (int k = 0; k < NF; ++k) {
    float w = rpw[(256 + k) * NF + c];
    a0 += O[0 * NF + k] * w; a1 += O[1 * NF + k] * w;
    a2 += O[2 * NF + k] * w; a3 += O[3 * NF + k] * w;
  }
  Q[(row0 + 0) * NF + c] = a0; Q[(row0 + 1) * NF + c] = a1;
  Q[(row0 + 2) * NF + c] = a2; Q[(row0 + 3) * NF + c] = a3;
  a0 = a1 = a2 = a3 = 0.f;
#pragma unroll 8
  for (int k = 0; k < NF; ++k) {
    float w = rpw[(512 + k) * NF + c];
    a0 += O[0 * NF + k] * w; a1 += O[1 * NF + k] * w;
    a2 += O[2 * NF + k] * w; a3 += O[3 * NF + k] * w;
  }
  R[(row0 + 0) * NF + c] = a0; R[(row0 + 1) * NF + c] = a1;
  R[(row0 + 2) * NF + c] = a2; R[(row0 + 3) * NF + c] = a3;
}

// ---------------------------------------------------------------------------
// Relation chain, bf16x3 split MFMA, software-pipelined (UNCHANGED from R5:
// 72 us proven; ROWS=32, X aliased onto H, 33.8KB LDS -> 4 blocks/CU).
// ---------------------------------------------------------------------------
#define ROWS 32
#define NRT 2
#define HSTR 264
#define XSTR 72

__global__ __launch_bounds__(256, 4) void rel_chain_mfma(
    const float* __restrict__ attrs, const float* __restrict__ states,
    const float* __restrict__ rel_attrs,
    const ushort_t* __restrict__ F0h, const ushort_t* __restrict__ F0l,
    const float* __restrict__ b0,
    const ushort_t* __restrict__ F1h, const ushort_t* __restrict__ F1l,
    const float* __restrict__ b1,
    const ushort_t* __restrict__ F2h, const ushort_t* __restrict__ F2l,
    float* __restrict__ P)
{
  __shared__ __align__(16) ushort_t Hh[ROWS * HSTR];
  __shared__ __align__(16) ushort_t Hl[ROWS * HSTR];
  ushort_t* Xh = Hh;
  ushort_t* Xl = Hl;

  int tid  = threadIdx.x;
  int wave = tid >> 6;
  int lane = tid & 63;
  int quad = lane >> 4;
  int l16  = lane & 15;
  int row0 = blockIdx.x * ROWS;

  for (int idx = tid; idx < ROWS * 64; idx += 256) {
    int r = idx >> 6, k = idx & 63;
    int grow = row0 + r;
    int j = grow & 63, i = (grow >> 6) & 63, b = grow >> 12;
    float v = 0.f;
    if (k < RELD)                     v = rel_attrs[(size_t)grow * RELD + k];
    else if (k < RELD + STATE)        v = states[(b * NN + i) * STATE + (k - RELD)]
                                        - states[(b * NN + j) * STATE + (k - RELD)];
    else if (k < RELD + STATE + ATTR) v = attrs[(b * NN + i) * ATTR + (k - RELD - STATE)];
    else if (k < 33)                  v = attrs[(b * NN + j) * ATTR + (k - RELD - STATE - ATTR)];
    ushort_t h, l; split2(v, h, l);
    Xh[r * XSTR + k] = h;
    Xl[r * XSTR + k] = l;
  }
  __syncthreads();

  floatx4 acc[NRT][4];

#define ZERO_ACC() do { \
  _Pragma("unroll") for (int rt = 0; rt < NRT; ++rt) \
  _Pragma("unroll") for (int ct = 0; ct < 4; ++ct) acc[rt][ct] = (floatx4)(0.f); } while (0)

#define STAGE(S, AH, AL, ASTR, BH, BL) do { \
  bf16x8 ah[2][NRT], al[2][NRT], bh[2][4], bl[2][4]; \
  _Pragma("unroll") for (int ct = 0; ct < 4; ++ct) { \
    bh[0][ct] = *(const bf16x8*)((BH) + (size_t)((wave * 4 + ct) * 64 + lane) * 8); \
    bl[0][ct] = *(const bf16x8*)((BL) + (size_t)((wave * 4 + ct) * 64 + lane) * 8); } \
  _Pragma("unroll") for (int rt = 0; rt < NRT; ++rt) { \
    ah[0][rt] = *(const bf16x8*)(&(AH)[(rt * 16 + l16) * (ASTR) + quad * 8]); \
    al[0][rt] = *(const bf16x8*)(&(AL)[(rt * 16 + l16) * (ASTR) + quad * 8]); } \
  _Pragma("unroll") \
  for (int s = 0; s < (S); ++s) { \
    int cur = s & 1, nxt = cur ^ 1; \
    if (s + 1 < (S)) { \
      _Pragma("unroll") for (int ct = 0; ct < 4; ++ct) { \
        bh[nxt][ct] = *(const bf16x8*)((BH) + (size_t)(((s + 1) * 16 + wave * 4 + ct) * 64 + lane) * 8); \
        bl[nxt][ct] = *(const bf16x8*)((BL) + (size_t)(((s + 1) * 16 + wave * 4 + ct) * 64 + lane) * 8); } \
      _Pragma("unroll") for (int rt = 0; rt < NRT; ++rt) { \
        ah[nxt][rt] = *(const bf16x8*)(&(AH)[(rt * 16 + l16) * (ASTR) + (s + 1) * 32 + quad * 8]); \
        al[nxt][rt] = *(const bf16x8*)(&(AL)[(rt * 16 + l16) * (ASTR) + (s + 1) * 32 + quad * 8]); } } \
    _Pragma("unroll") for (int rt = 0; rt < NRT; ++rt) \
    _Pragma("unroll") for (int ct = 0; ct < 4; ++ct) { \
      acc[rt][ct] = __builtin_amdgcn_mfma_f32_16x16x32_bf16(ah[cur][rt], bh[cur][ct], acc[rt][ct], 0, 0, 0); \
      acc[rt][ct] = __builtin_amdgcn_mfma_f32_16x16x32_bf16(ah[cur][rt], bl[cur][ct], acc[rt][ct], 0, 0, 0); \
      acc[rt][ct] = __builtin_amdgcn_mfma_f32_16x16x32_bf16(al[cur][rt], bh[cur][ct], acc[rt][ct], 0, 0, 0); } \
  } } while (0)

  // ---- stage 1: H = ReLU(X @ W0 + b0), K=64 (padded)
  ZERO_ACC();
  STAGE(2, Xh, Xl, XSTR, F0h, F0l);
  __syncthreads();  // X reads done before H overwrites the aliased region
#pragma unroll
  for (int ct = 0; ct < 4; ++ct) {
    int col = wave * 64 + ct * 16 + l16;
    float bias = b0[col];
#pragma unroll
    for (int rt = 0; rt < NRT; ++rt)
#pragma unroll
      for (int r = 0; r < 4; ++r) {
        int row = rt * 16 + quad * 4 + r;
        float h = fmaxf(acc[rt][ct][r] + bias, 0.f);
        split2(h, Hh[row * HSTR + col], Hl[row * HSTR + col]);
      }
  }
  __syncthreads();

  // ---- stage 2: E = ReLU(H @ W1 + b1), K=256
  ZERO_ACC();
  STAGE(8, Hh, Hl, HSTR, F1h, F1l);
  __syncthreads();
#pragma unroll
  for (int ct = 0; ct < 4; ++ct) {
    int col = wave * 64 + ct * 16 + l16;
    float bias = b1[col];
#pragma unroll
    for (int rt = 0; rt < NRT; ++rt)
#pragma unroll
      for (int r = 0; r < 4; ++r) {
        int row = rt * 16 + quad * 4 + r;
        float e = fmaxf(acc[rt][ct][r] + bias, 0.f);
        split2(e, Hh[row * HSTR + col], Hl[row * HSTR + col]);
      }
  }
  __syncthreads();

  // ---- stage 3: P = E @ W2 (rp_b folded into Q), K=256, fp32 out
  ZERO_ACC();
  STAGE(8, Hh, Hl, HSTR, F2h, F2l);
#pragma unroll
  for (int ct = 0; ct < 4; ++ct) {
    int col = wave * 64 + ct * 16 + l16;
#pragma unroll
    for (int rt = 0; rt < NRT; ++rt)
#pragma unroll
      for (int r = 0; r < 4; ++r) {
        int row = rt * 16 + quad * 4 + r;
        P[(size_t)(row0 + row) * NF + col] = acc[rt][ct][r];
      }
  }
#undef ZERO_ACC
#undef STAGE
}

// ---------------------------------------------------------------------------
// Fused agg + update + Q/R (one kernel per pstep; no `part` round-trip).
// Block owns 4 obj-rows (same b since 4|64): computes agg = sum_j ReLU(P+Q+R)
// by streaming its 256KB P slice (L3-resident), then update GEMM from LDS,
// then Q'/R' GEMMs. Qo/Ro are separate buffers (blocks read all R rows of b).
// ---------------------------------------------------------------------------
__device__ __forceinline__ void aggupd_head(
    const float* __restrict__ P, const float* __restrict__ obj,
    const float* __restrict__ Q, const float* __restrict__ R,
    const float* __restrict__ ppw, const float* __restrict__ ppb,
    float* A, float* G, int row0, int c,
    float& o0, float& o1, float& o2, float& o3)
{
  int b = row0 >> 6;
  float q0 = Q[(row0 + 0) * NF + c], q1 = Q[(row0 + 1) * NF + c];
  float q2 = Q[(row0 + 2) * NF + c], q3 = Q[(row0 + 3) * NF + c];
  const float* Pb = P + (size_t)row0 * NN * NF + c;
  const float* Rb = R + (size_t)(b * NN) * NF + c;
  float s0 = 0.f, s1 = 0.f, s2 = 0.f, s3 = 0.f;
#pragma unroll 4
  for (int j = 0; j < NN; ++j) {
    float rv = Rb[(size_t)j * NF];
    s0 += fmaxf(Pb[(size_t)(0 * NN + j) * NF] + q0 + rv, 0.f);
    s1 += fmaxf(Pb[(size_t)(1 * NN + j) * NF] + q1 + rv, 0.f);
    s2 += fmaxf(Pb[(size_t)(2 * NN + j) * NF] + q2 + rv, 0.f);
    s3 += fmaxf(Pb[(size_t)(3 * NN + j) * NF] + q3 + rv, 0.f);
  }
  A[0 * NF + c] = obj[(row0 + 0) * NF + c];
  A[1 * NF + c] = obj[(row0 + 1) * NF + c];
  A[2 * NF + c] = obj[(row0 + 2) * NF + c];
  A[3 * NF + c] = obj[(row0 + 3) * NF + c];
  G[0 * NF + c] = s0; G[1 * NF + c] = s1; G[2 * NF + c] = s2; G[3 * NF + c] = s3;
  __syncthreads();
  float a0, a1, a2, a3;
  a0 = a1 = a2 = a3 = ppb[c];
#pragma unroll 8
  for (int k = 0; k < NF; ++k) {
    float w = ppw[k * NF + c];
    a0 += A[0 * NF + k] * w; a1 += A[1 * NF + k] * w;
    a2 += A[2 * NF + k] * w; a3 += A[3 * NF + k] * w;
  }
#pragma unroll 8
  for (int k = 0; k < NF; ++k) {
    float w = ppw[(NF + k) * NF + c];
    a0 += G[0 * NF + k] * w; a1 += G[1 * NF + k] * w;
    a2 += G[2 * NF + k] * w; a3 += G[3 * NF + k] * w;
  }
  o0 = fmaxf(a0, 0.f); o1 = fmaxf(a1, 0.f); o2 = fmaxf(a2, 0.f); o3 = fmaxf(a3, 0.f);
}

__global__ __launch_bounds__(256) void aggupd_qr_kernel(
    const float* __restrict__ P, const float* __restrict__ obj,
    const float* __restrict__ Q, const float* __restrict__ R,
    const float* __restrict__ ppw, const float* __restrict__ ppb,
    const float* __restrict__ rpw, const float* __restrict__ rpb,
    float* __restrict__ obj_out, float* __restrict__ Qo, float* __restrict__ Ro)
{
  __shared__ float A[4 * NF];
  __shared__ float G[4 * NF];
  int c = threadIdx.x;
  int row0 = blockIdx.x * 4;
  float o0, o1, o2, o3;
  aggupd_head(P, obj, Q, R, ppw, ppb, A, G, row0, c, o0, o1, o2, o3);
  __syncthreads();                 // old A reads done
  A[0 * NF + c] = o0; A[1 * NF + c] = o1; A[2 * NF + c] = o2; A[3 * NF + c] = o3;
  obj_out[(row0 + 0) * NF + c] = o0; obj_out[(row0 + 1) * NF + c] = o1;
  obj_out[(row0 + 2) * NF + c] = o2; obj_out[(row0 + 3) * NF + c] = o3;
  __syncthreads();
  float a0, a1, a2, a3;
  a0 = a1 = a2 = a3 = rpb[c];
#pragma unroll 8
  for (int k = 0; k < NF; ++k) {
    float w = rpw[(256 + k) * NF + c];
    a0 += A[0 * NF + k] * w; a1 += A[1 * NF + k] * w;
    a2 += A[2 * NF + k] * w; a3 += A[3 * NF + k] * w;
  }
  Qo[(row0 + 0) * NF + c] = a0; Qo[(row0 + 1) * NF + c] = a1;
  Qo[(row0 + 2) * NF + c] = a2; Qo[(row0 + 3) * NF + c] = a3;
  a0 = a1 = a2 = a3 = 0.f;
#pragma unroll 8
  for (int k = 0; k < NF; ++k) {
    float w = rpw[(512 + k) * NF + c];
    a0 += A[0 * NF + k] * w; a1 += A[1 * NF + k] * w;
    a2 += A[2 * NF + k] * w; a3 += A[3 * NF + k] * w;
  }
  Ro[(row0 + 0) * NF + c] = a0; Ro[(row0 + 1) * NF + c] = a1;
  Ro[(row0 + 2) * NF + c] = a2; Ro[(row0 + 3) * NF + c] = a3;
}

__global__ __launch_bounds__(256) void aggupd_pred_kernel(
    const float* __restrict__ P, const float* __restrict__ obj,
    const float* __restrict__ Q, const float* __restrict__ R,
    const float* __restrict__ ppw, const float* __restrict__ ppb,
    const float* __restrict__ w0, const float* __restrict__ b0,
    const float* __restrict__ w1, const float* __restrict__ b1,
    float* __restrict__ out)
{
  __shared__ float A[4 * NF];
  __shared__ float G[4 * NF];
  int c = threadIdx.x;
  int row0 = blockIdx.x * 4;
  float o0, o1, o2, o3;
  aggupd_head(P, obj, Q, R, ppw, ppb, A, G, row0, c, o0, o1, o2, o3);
  __syncthreads();                 // old A reads done
  A[0 * NF + c] = o0; A[1 * NF + c] = o1; A[2 * NF + c] = o2; A[3 * NF + c] = o3;
  __syncthreads();
  // T = ReLU(obj2 @ w0 + b0) -> G (G reads finished before the barrier above)
  float a0, a1, a2, a3;
  a0 = a1 = a2 = a3 = b0[c];
#pragma unroll 8
  for (int k = 0; k < NF; ++k) {
    float w = w0[k * NF + c];
    a0 += A[0 * NF + k] * w; a1 += A[1 * NF + k] * w;
    a2 += A[2 * NF + k] * w; a3 += A[3 * NF + k] * w;
  }
  G[0 * NF + c] = fmaxf(a0, 0.f); G[1 * NF + c] = fmaxf(a1, 0.f);
  G[2 * NF + c] = fmaxf(a2, 0.f); G[3 * NF + c] = fmaxf(a3, 0.f);
  __syncthreads();
  if (c < 4 * GG) {
    int r = c >> 5, g = c & 31;
    float a = b1[g];
    const float* Tr = G + r * NF;
#pragma unroll 8
    for (int k = 0; k < NF; ++k) a += Tr[k] * w1[k * GG + g];
    out[(row0 + r) * GG + g] = tanhf(a);
  }
}

extern "C" void kernel_launch(void* const* d_in, const int* in_sizes, int n_in,
                              void* d_out, int out_size, void* d_ws, size_t ws_size,
                              hipStream_t stream)
{
  const float* attrs     = (const float*)d_in[0];
  const float* states    = (const float*)d_in[1];
  const float* rel_attrs = (const float*)d_in[2];
  // d_in[3] = pstep (==2, structural)
  const float* enc_w0  = (const float*)d_in[4];
  const float* enc_b0  = (const float*)d_in[5];
  const float* enc_w1  = (const float*)d_in[6];
  const float* enc_b1  = (const float*)d_in[7];
  const float* rel_w0  = (const float*)d_in[8];
  const float* rel_b0  = (const float*)d_in[9];
  const float* rel_w1  = (const float*)d_in[10];
  const float* rel_b1  = (const float*)d_in[11];
  const float* rp_w    = (const float*)d_in[12];
  const float* rp_b    = (const float*)d_in[13];
  const float* pp_w    = (const float*)d_in[14];
  const float* pp_b    = (const float*)d_in[15];
  const float* pred_w0 = (const float*)d_in[16];
  const float* pred_b0 = (const float*)d_in[17];
  const float* pred_w1 = (const float*)d_in[18];
  const float* pred_b1 = (const float*)d_in[19];
  float* out = (float*)d_out;

  char* ws = (char*)d_ws;
  float* P    = (float*)ws;                                  // 64 MB
  float* obj0 = P + (size_t)NROWS_REL * NF;
  float* obj1 = obj0 + NROWS_OBJ * NF;
  float* Q0   = obj1 + NROWS_OBJ * NF;
  float* R0   = Q0 + NROWS_OBJ * NF;
  float* Q1   = R0 + NROWS_OBJ * NF;
  float* R1   = Q1 + NROWS_OBJ * NF;
  ushort_t* F0h = (ushort_t*)(R1 + NROWS_OBJ * NF);
  ushort_t* F0l = F0h + F0_ELEMS;
  ushort_t* F1h = F0l + F0_ELEMS;
  ushort_t* F1l = F1h + F1_ELEMS;
  ushort_t* F2h = F1l + F1_ELEMS;
  ushort_t* F2l = F2h + F1_ELEMS;

  enc_qr_prep_kernel<<<NROWS_OBJ / 4, 256, 0, stream>>>(
      attrs, states, enc_w0, enc_b0, enc_w1, enc_b1, rp_w, rp_b,
      rel_w0, rel_w1, F0h, F0l, F1h, F1l, F2h, F2l, obj0, Q0, R0);
  rel_chain_mfma<<<NROWS_REL / ROWS, 256, 0, stream>>>(attrs, states, rel_attrs,
                                                       F0h, F0l, rel_b0,
                                                       F1h, F1l, rel_b1,
                                                       F2h, F2l, P);
  // pstep 1: agg + update + Q/R (double-buffered Q/R to avoid cross-block race)
  aggupd_qr_kernel<<<NROWS_OBJ / 4, 256, 0, stream>>>(P, obj0, Q0, R0,
                                                      pp_w, pp_b, rp_w, rp_b,
                                                      obj1, Q1, R1);
  // pstep 2: agg + update + predictor + tanh
  aggupd_pred_kernel<<<NROWS_OBJ / 4, 256, 0, stream>>>(P, obj1, Q1, R1,
                                                        pp_w, pp_b,
                                                        pred_w0, pred_b0,
                                                        pred_w1, pred_b1, out);
}